// Round 12
// baseline (744.891 us; speedup 1.0000x reference)
//
#include <hip/hip_runtime.h>

typedef long long i64;
typedef unsigned int u32;
typedef unsigned short u16;

#define Bq 16
#define Cq 512
#define Hq 32
#define Wq 32
#define Nq 1024
#define MIDq 128
#define XPBq 591872   // 34*34*512 per-batch padded-transposed stride

typedef __attribute__((ext_vector_type(8))) short bf16x8;
typedef __attribute__((ext_vector_type(16))) float f32x16;

// float -> bf16 (RNE) and back
static __device__ __forceinline__ u16 f2bf(float f) {
  u32 u = __float_as_uint(f);
  u = (u + 0x7FFFu + ((u >> 16) & 1u)) >> 16;
  return (u16)u;
}
static __device__ __forceinline__ float bf2f(u16 h) {
  return __uint_as_float(((u32)h) << 16);
}

// ---------------- merged prep: 5 weight splits + 3x3 repack + DCT/mask ----------------
__global__ __launch_bounds__(256) void k_prep(
    const float* __restrict__ rgb_w, const float* __restrict__ dsm_w,
    const float* __restrict__ q_w, const float* __restrict__ k_w,
    const float* __restrict__ v_w, const float* __restrict__ sp_w,
    u16* __restrict__ rw_h, u16* __restrict__ rw_l,
    u16* __restrict__ dw_h, u16* __restrict__ dw_l,
    u16* __restrict__ qw_h, u16* __restrict__ qw_l,
    u16* __restrict__ kw_h, u16* __restrict__ kw_l,
    u16* __restrict__ vw_h, u16* __restrict__ vw_l,
    u16* __restrict__ w9h, u16* __restrict__ w9l,
    float* __restrict__ Dm, float* __restrict__ lm) {
  int blk = blockIdx.x, tid = threadIdx.x;
  if (blk < 1280) {
    int wi = blk >> 8;
    const float* src = wi == 0 ? rgb_w : wi == 1 ? dsm_w : wi == 2 ? q_w : wi == 3 ? k_w : v_w;
    u16* hi = wi == 0 ? rw_h : wi == 1 ? dw_h : wi == 2 ? qw_h : wi == 3 ? kw_h : vw_h;
    u16* lo = wi == 0 ? rw_l : wi == 1 ? dw_l : wi == 2 ? qw_l : wi == 3 ? kw_l : vw_l;
    i64 idx = ((i64)(blk & 255) * 256 + tid) * 4;
    float4 f = *(const float4*)(src + idx);
    ushort4 h, l;
    h.x = f2bf(f.x); l.x = f2bf(f.x - bf2f(h.x));
    h.y = f2bf(f.y); l.y = f2bf(f.y - bf2f(h.y));
    h.z = f2bf(f.z); l.z = f2bf(f.z - bf2f(h.z));
    h.w = f2bf(f.w); l.w = f2bf(f.w - bf2f(h.w));
    *(ushort4*)(hi + idx) = h;
    *(ushort4*)(lo + idx) = l;
  } else if (blk < 1536) {
    int idx = (blk - 1280) * 256 + tid;   // 65536 total
    int o = idx >> 7;
    int c4 = (idx & 127) << 2;
    float vals[4][9];
#pragma unroll
    for (int j = 0; j < 4; j++) {
      const float* wp = sp_w + ((i64)o * Cq + c4 + j) * 9;
#pragma unroll
      for (int t = 0; t < 9; t++) vals[j][t] = wp[t];
    }
#pragma unroll
    for (int t = 0; t < 9; t++) {
      ushort4 h, l;
      h.x = f2bf(vals[0][t]); l.x = f2bf(vals[0][t] - bf2f(h.x));
      h.y = f2bf(vals[1][t]); l.y = f2bf(vals[1][t] - bf2f(h.y));
      h.z = f2bf(vals[2][t]); l.z = f2bf(vals[2][t] - bf2f(h.z));
      h.w = f2bf(vals[3][t]); l.w = f2bf(vals[3][t] - bf2f(h.w));
      i64 od = (i64)t * (Cq * Cq) + (i64)o * Cq + c4;
      *(ushort4*)(w9h + od) = h;
      *(ushort4*)(w9l + od) = l;
    }
  } else {
#pragma unroll
    for (int q4 = 0; q4 < 4; q4++) {
      int t = tid * 4 + q4;          // 0..1023
      int i = t >> 5, j = t & 31;
      float v = cosf(3.14159265358979323846f * (2.0f * j + 1.0f) * (float)i / 64.0f) * 0.25f;
      if (i == 0) v *= 0.7071067811865476f;
      Dm[t] = v;
      float yy = i * (1.0f / 31.0f), xx = j * (1.0f / 31.0f);
      float rr = sqrtf(yy * yy + xx * xx) * 0.7071067811865476f;
      lm[t] = (rr <= 0.35f) ? 1.0f : 0.0f;
    }
  }
}

// ---------------- zero only the 132 border rows of xpad (hi & lo) ----------------
__global__ __launch_bounds__(64) void k_zero_border(u16* __restrict__ xp) {
  int i = blockIdx.x;     // 0..131 border-row index
  int b = blockIdx.y;     // batch
  int arr = blockIdx.z;   // 0 hi, 1 lo
  int pr;
  if (i < 34) pr = i;
  else if (i < 68) pr = 33 * 34 + (i - 34);
  else { int j = i - 68; pr = (1 + (j >> 1)) * 34 + (j & 1) * 33; }
  u16* p = xp + (i64)arr * ((i64)Bq * XPBq) + (i64)b * XPBq + (i64)pr * Cq;
  *(uint4*)(p + threadIdx.x * 8) = (uint4){0u, 0u, 0u, 0u};
}

// ---------------- bf16x3 MFMA GEMM (32x32x16), 256 threads, 4 waves x 64x64 ----------------
// C[b][M][N] = A[b][M][K] * B[b][N][K]^T
// a_mode/b_mode: 0 = pre-split bf16 hi/lo k-contiguous [M|N][K]; 1 = fp32 [K][M|N] transposed+split on the fly.
// bias_mode: 0 none, 1 bias[row], 2 bias[col].
// out_mode: 0 fp32 [M][N]; 1 bf16 hi/lo split [M][N]; 2 bf16 hi/lo pad-transposed xpad layout.
__global__ __launch_bounds__(256) void k_gemm(
    const u16* __restrict__ Ahi, const u16* __restrict__ Alo,
    const float* __restrict__ Af32, int a_mode, i64 sAb,
    const u16* __restrict__ Bhi, const u16* __restrict__ Blo,
    const float* __restrict__ Bf32, int b_mode, i64 sBb,
    const float* __restrict__ bias, int bias_mode, float scale,
    int M, int N, int K,
    float* __restrict__ Cf, u16* __restrict__ Chi, u16* __restrict__ Clo,
    i64 sCb, int out_mode) {
  __shared__ __align__(16) u16 As_h[128][40];
  __shared__ __align__(16) u16 As_l[128][40];
  __shared__ __align__(16) u16 Bs_h[128][40];
  __shared__ __align__(16) u16 Bs_l[128][40];
  int tid = threadIdx.x;
  // XCD-aware bijective block swizzle
  int gx = gridDim.x, gxy = gx * gridDim.y;
  int nwg = gxy * gridDim.z;
  int orig = blockIdx.x + gx * blockIdx.y + gxy * blockIdx.z;
  int wg = (nwg & 7) ? orig : ((orig & 7) * (nwg >> 3) + (orig >> 3));
  int b = wg / gxy;
  int rem = wg - b * gxy;
  int m0 = (rem / gx) << 7;
  int n0 = (rem - (rem / gx) * gx) << 7;
  const u16* pAhi = Ahi + (i64)b * (a_mode ? 0 : sAb);
  const u16* pAlo = Alo + (i64)b * (a_mode ? 0 : sAb);
  const float* pAf = a_mode ? (Af32 + (i64)b * sAb) : nullptr;
  const u16* pBhi = Bhi + (i64)b * (b_mode ? 0 : sBb);
  const u16* pBlo = Blo + (i64)b * (b_mode ? 0 : sBb);
  const float* pBf = b_mode ? (Bf32 + (i64)b * sBb) : nullptr;
  int lane = tid & 63;
  int wid = tid >> 6;              // 0..3
  int wm = (wid & 1) << 6;
  int wn = (wid >> 1) << 6;
  int l31 = lane & 31;
  int kg = (lane >> 5) << 3;       // 0 or 8
  f32x16 acc[2][2];
#pragma unroll
  for (int mi = 0; mi < 2; mi++)
#pragma unroll
    for (int nj = 0; nj < 2; nj++)
      acc[mi][nj] = (f32x16){0.f,0.f,0.f,0.f,0.f,0.f,0.f,0.f,0.f,0.f,0.f,0.f,0.f,0.f,0.f,0.f};

  for (int k0 = 0; k0 < K; k0 += 32) {
    // ---- stage A ----
    if (a_mode == 0) {
#pragma unroll
      for (int i = 0; i < 4; i++) {
        int r = ((i & 1) << 6) + (tid >> 2);
        int seg = tid & 3;
        const u16* src = (i < 2) ? pAhi : pAlo;
        uint4 val = *(const uint4*)(src + (i64)(m0 + r) * K + k0 + seg * 8);
        if (i < 2) *(uint4*)&As_h[r][seg * 8] = val;
        else       *(uint4*)&As_l[r][seg * 8] = val;
      }
    } else {
      int cs = tid >> 6, ns = tid & 63;
      const float* src = pAf + (i64)(k0 + cs * 8) * M + m0 + ns * 2;
      float2 f[8];
#pragma unroll
      for (int j = 0; j < 8; j++) f[j] = *(const float2*)(src + (i64)j * M);
#pragma unroll
      for (int i = 0; i < 2; i++) {
        union { u16 u[8]; uint4 v; } hh, ll;
#pragma unroll
        for (int j = 0; j < 8; j++) {
          float x = i ? f[j].y : f[j].x;
          u16 h = f2bf(x);
          hh.u[j] = h;
          ll.u[j] = (u16)(__float_as_uint(x - bf2f(h)) >> 16);
        }
        *(uint4*)&As_h[2 * ns + i][8 * cs] = hh.v;
        *(uint4*)&As_l[2 * ns + i][8 * cs] = ll.v;
      }
    }
    // ---- stage B ----
    if (b_mode == 0) {
#pragma unroll
      for (int i = 0; i < 4; i++) {
        int r = ((i & 1) << 6) + (tid >> 2);
        int seg = tid & 3;
        const u16* src = (i < 2) ? pBhi : pBlo;
        uint4 val = *(const uint4*)(src + (i64)(n0 + r) * K + k0 + seg * 8);
        if (i < 2) *(uint4*)&Bs_h[r][seg * 8] = val;
        else       *(uint4*)&Bs_l[r][seg * 8] = val;
      }
    } else {
      int cs = tid >> 6, ns = tid & 63;
      const float* src = pBf + (i64)(k0 + cs * 8) * N + n0 + ns * 2;
      float2 f[8];
#pragma unroll
      for (int j = 0; j < 8; j++) f[j] = *(const float2*)(src + (i64)j * N);
#pragma unroll
      for (int i = 0; i < 2; i++) {
        union { u16 u[8]; uint4 v; } hh, ll;
#pragma unroll
        for (int j = 0; j < 8; j++) {
          float x = i ? f[j].y : f[j].x;
          u16 h = f2bf(x);
          hh.u[j] = h;
          ll.u[j] = (u16)(__float_as_uint(x - bf2f(h)) >> 16);
        }
        *(uint4*)&Bs_h[2 * ns + i][8 * cs] = hh.v;
        *(uint4*)&Bs_l[2 * ns + i][8 * cs] = ll.v;
      }
    }
    __syncthreads();
#pragma unroll
    for (int kstep = 0; kstep < 2; kstep++) {
      int kc = kstep * 16 + kg;
      bf16x8 ah[2], al[2], bh[2], bl[2];
#pragma unroll
      for (int mi = 0; mi < 2; mi++) {
        int row = wm + mi * 32 + l31;
        ah[mi] = *(const bf16x8*)&As_h[row][kc];
        al[mi] = *(const bf16x8*)&As_l[row][kc];
      }
#pragma unroll
      for (int nj = 0; nj < 2; nj++) {
        int row = wn + nj * 32 + l31;
        bh[nj] = *(const bf16x8*)&Bs_h[row][kc];
        bl[nj] = *(const bf16x8*)&Bs_l[row][kc];
      }
#pragma unroll
      for (int mi = 0; mi < 2; mi++)
#pragma unroll
        for (int nj = 0; nj < 2; nj++) {
          acc[mi][nj] = __builtin_amdgcn_mfma_f32_32x32x16_bf16(ah[mi], bh[nj], acc[mi][nj], 0, 0, 0);
          acc[mi][nj] = __builtin_amdgcn_mfma_f32_32x32x16_bf16(ah[mi], bl[nj], acc[mi][nj], 0, 0, 0);
          acc[mi][nj] = __builtin_amdgcn_mfma_f32_32x32x16_bf16(al[mi], bh[nj], acc[mi][nj], 0, 0, 0);
        }
    }
    __syncthreads();
  }

  // epilogue: 32x32 C/D layout col=lane&31, row=(reg&3)+8*(reg>>2)+4*(lane>>5)
#pragma unroll
  for (int mi = 0; mi < 2; mi++)
#pragma unroll
    for (int nj = 0; nj < 2; nj++) {
      int col_g = n0 + wn + nj * 32 + l31;
#pragma unroll
      for (int g = 0; g < 4; g++) {
        int row_b = m0 + wm + mi * 32 + g * 8 + ((lane >> 5) << 2);
        float v4[4];
#pragma unroll
        for (int r = 0; r < 4; r++) {
          float val = acc[mi][nj][g * 4 + r] * scale;
          if (bias_mode == 1) val += bias[row_b + r];
          else if (bias_mode == 2) val += bias[col_g];
          v4[r] = val;
        }
        if (out_mode == 0) {
#pragma unroll
          for (int r = 0; r < 4; r++)
            Cf[(i64)b * sCb + (i64)(row_b + r) * N + col_g] = v4[r];
        } else if (out_mode == 1) {
#pragma unroll
          for (int r = 0; r < 4; r++) {
            i64 o = (i64)b * sCb + (i64)(row_b + r) * N + col_g;
            u16 h = f2bf(v4[r]);
            Chi[o] = h;
            Clo[o] = f2bf(v4[r] - bf2f(h));
          }
        } else {
          int pr = ((col_g >> 5) + 1) * 34 + (col_g & 31) + 1;
          i64 o = (i64)b * sCb + (i64)pr * Cq + row_b;
          ushort4 hh, ll;
          hh.x = f2bf(v4[0]); ll.x = f2bf(v4[0] - bf2f(hh.x));
          hh.y = f2bf(v4[1]); ll.y = f2bf(v4[1] - bf2f(hh.y));
          hh.z = f2bf(v4[2]); ll.z = f2bf(v4[2] - bf2f(hh.z));
          hh.w = f2bf(v4[3]); ll.w = f2bf(v4[3] - bf2f(hh.w));
          *(ushort4*)(Chi + o) = hh;
          *(ushort4*)(Clo + o) = ll;
        }
      }
    }
}

// ---------------- MFMA 3x3 conv (32x32x16), 256 threads, B-super-tile over 9 taps ----------------
__global__ __launch_bounds__(256) void k_conv3_mfma(
    const u16* __restrict__ Wh, const u16* __restrict__ Wl,
    const u16* __restrict__ Xh, const u16* __restrict__ Xl,
    const float* __restrict__ bias, float* __restrict__ out) {
  __shared__ __align__(16) u16 As_h[128][40];
  __shared__ __align__(16) u16 As_l[128][40];
  __shared__ __align__(16) u16 Bs_h[204][40];
  __shared__ __align__(16) u16 Bs_l[204][40];
  int tid = threadIdx.x;
  // XCD-aware bijective block swizzle
  int gx = gridDim.x, gxy = gx * gridDim.y;
  int nwg = gxy * gridDim.z;
  int orig = blockIdx.x + gx * blockIdx.y + gxy * blockIdx.z;
  int wg = (nwg & 7) ? orig : ((orig & 7) * (nwg >> 3) + (orig >> 3));
  int b = wg / gxy;
  int rem = wg - b * gxy;
  int m0 = (rem / gx) << 7;                // out-channel tile
  int n0 = (rem - (rem / gx) * gx) << 7;   // pixel tile (4 image rows)
  int lane = tid & 63;
  int wid = tid >> 6;                      // 0..3
  int wm = (wid & 1) << 6;
  int wn = (wid >> 1) << 6;
  int l31 = lane & 31;
  int kg = (lane >> 5) << 3;
  int yb = n0 >> 5;
  const u16* pXh = Xh + (i64)b * XPBq + (i64)(yb * 34) * Cq;  // 204-row window
  const u16* pXl = Xl + (i64)b * XPBq + (i64)(yb * 34) * Cq;
  int bbase[2];
#pragma unroll
  for (int nj = 0; nj < 2; nj++) {
    int nloc = wn + nj * 32 + l31;        // 0..127
    bbase[nj] = (nloc >> 5) * 34 + (nloc & 31);
  }
  f32x16 acc[2][2];
#pragma unroll
  for (int mi = 0; mi < 2; mi++)
#pragma unroll
    for (int nj = 0; nj < 2; nj++)
      acc[mi][nj] = (f32x16){0.f,0.f,0.f,0.f,0.f,0.f,0.f,0.f,0.f,0.f,0.f,0.f,0.f,0.f,0.f,0.f};

  for (int c0 = 0; c0 < Cq; c0 += 32) {
    // ---- stage B super-tile: 204 rows x 32 ch (hi + lo), once per c0 ----
    for (int e = tid; e < 816; e += 256) {   // 204 rows * 4 uint4
      int row = e >> 2, q = e & 3;
      i64 src = (i64)row * Cq + c0 + q * 8;
      *(uint4*)&Bs_h[row][q * 8] = *(const uint4*)(pXh + src);
      *(uint4*)&Bs_l[row][q * 8] = *(const uint4*)(pXl + src);
    }
    for (int tap = 0; tap < 9; tap++) {
      int doff = (tap / 3) * 34 + (tap % 3);
      // ---- stage A: weights for this (tap, c0), 128 rows x 32 ch ----
      {
        int r = tid >> 1, q0 = (tid & 1) << 1;
        i64 wo = (i64)tap * (Cq * Cq) + (i64)(m0 + r) * Cq + c0;
        *(uint4*)&As_h[r][q0 * 8]       = *(const uint4*)(Wh + wo + q0 * 8);
        *(uint4*)&As_h[r][(q0 + 1) * 8] = *(const uint4*)(Wh + wo + (q0 + 1) * 8);
        *(uint4*)&As_l[r][q0 * 8]       = *(const uint4*)(Wl + wo + q0 * 8);
        *(uint4*)&As_l[r][(q0 + 1) * 8] = *(const uint4*)(Wl + wo + (q0 + 1) * 8);
      }
      __syncthreads();
#pragma unroll
      for (int kstep = 0; kstep < 2; kstep++) {
        int kc = kstep * 16 + kg;
        bf16x8 ah[2], al[2], bh[2], bl[2];
#pragma unroll
        for (int mi = 0; mi < 2; mi++) {
          int row = wm + mi * 32 + l31;
          ah[mi] = *(const bf16x8*)&As_h[row][kc];
          al[mi] = *(const bf16x8*)&As_l[row][kc];
        }
#pragma unroll
        for (int nj = 0; nj < 2; nj++) {
          int row = bbase[nj] + doff;
          bh[nj] = *(const bf16x8*)&Bs_h[row][kc];
          bl[nj] = *(const bf16x8*)&Bs_l[row][kc];
        }
#pragma unroll
        for (int mi = 0; mi < 2; mi++)
#pragma unroll
          for (int nj = 0; nj < 2; nj++) {
            acc[mi][nj] = __builtin_amdgcn_mfma_f32_32x32x16_bf16(ah[mi], bh[nj], acc[mi][nj], 0, 0, 0);
            acc[mi][nj] = __builtin_amdgcn_mfma_f32_32x32x16_bf16(ah[mi], bl[nj], acc[mi][nj], 0, 0, 0);
            acc[mi][nj] = __builtin_amdgcn_mfma_f32_32x32x16_bf16(al[mi], bh[nj], acc[mi][nj], 0, 0, 0);
          }
      }
      __syncthreads();
    }
  }

#pragma unroll
  for (int mi = 0; mi < 2; mi++)
#pragma unroll
    for (int nj = 0; nj < 2; nj++) {
      int col_g = n0 + wn + nj * 32 + l31;
#pragma unroll
      for (int g = 0; g < 4; g++) {
        int row_b = m0 + wm + mi * 32 + g * 8 + ((lane >> 5) << 2);
#pragma unroll
        for (int r = 0; r < 4; r++) {
          float val = acc[mi][nj][g * 4 + r] + bias[row_b + r];
          out[(i64)b * (Cq * Nq) + (i64)(row_b + r) * Nq + col_g] = val;
        }
      }
    }
}

// ---------------- mean over N per (b,c): one wave per row ----------------
__global__ __launch_bounds__(256) void k_pool(const float* __restrict__ x, float* __restrict__ o) {
  int gw = (int)((blockIdx.x * 256 + threadIdx.x) >> 6);
  int ln = threadIdx.x & 63;
  const float* p = x + (i64)gw * Nq;
  float s = 0.f;
#pragma unroll
  for (int it = 0; it < 4; it++) {
    float4 v = *(const float4*)(p + ln * 4 + it * 256);
    s += v.x + v.y + v.z + v.w;
  }
#pragma unroll
  for (int off = 32; off > 0; off >>= 1) s += __shfl_xor(s, off, 64);
  if (ln == 0) o[gw] = s * (1.0f / 1024.0f);
}

// ---------------- gate MLP (32 blocks: 0-15 rgb, 16-31 dsm) ----------------
__global__ __launch_bounds__(128) void k_gate(
    const float* __restrict__ pooled, const float* __restrict__ w1,
    const float* __restrict__ b1, const float* __restrict__ w2,
    const float* __restrict__ b2, float* __restrict__ g) {
  __shared__ float pl[Cq];
  __shared__ float h[MIDq];
  int bb = blockIdx.x, tid = threadIdx.x;
  for (int c = tid; c < Cq; c += 128) pl[c] = pooled[bb * Cq + c];
  __syncthreads();
  float s = b1[tid];
  const float* wr = w1 + (i64)tid * Cq;
  for (int c = 0; c < Cq; c++) s = fmaf(wr[c], pl[c], s);
  h[tid] = fmaxf(s, 0.f);
  __syncthreads();
  if (tid < 2) {
    float t = b2[tid];
    const float* w2r = w2 + tid * MIDq;
    for (int m = 0; m < MIDq; m++) t = fmaf(w2r[m], h[m], t);
    g[bb * 2 + tid] = 1.0f / (1.0f + expf(-t));
  }
}

// ---------------- fused DCT -> gate -> iDCT per (b,c) 32x32 image ----------------
__global__ __launch_bounds__(256) void k_freq(
    const float* __restrict__ xr, const float* __restrict__ xd,
    float* __restrict__ yr, float* __restrict__ yd,
    const float* __restrict__ g_r, const float* __restrict__ g_d,
    const float* __restrict__ Dm, const float* __restrict__ lm) {
  __shared__ float Ds[32][36], Dt[32][36], Xs[32][36], T1[32][36];
  int bid = blockIdx.x;
  const float* x; float* y; const float* g;
  if (bid < Bq * Cq) {
    x = xr + (i64)bid * Nq; y = yr + (i64)bid * Nq; g = g_r + (bid >> 9) * 2;
  } else {
    int id = bid - Bq * Cq;
    x = xd + (i64)id * Nq; y = yd + (i64)id * Nq; g = g_d + (id >> 9) * 2;
  }
  int tid = threadIdx.x;
  int r_ = tid >> 3, j4 = (tid & 7) << 2;
  {
    float4 dv = *(const float4*)(Dm + tid * 4);
    *(float4*)&Ds[r_][j4] = dv;
    Dt[j4 + 0][r_] = dv.x; Dt[j4 + 1][r_] = dv.y;
    Dt[j4 + 2][r_] = dv.z; Dt[j4 + 3][r_] = dv.w;
    *(float4*)&Xs[r_][j4] = *(const float4*)(x + tid * 4);
  }
  float gl = g[0], gh = g[1];
  __syncthreads();
  float a0 = 0, a1 = 0, a2 = 0, a3 = 0;
#pragma unroll
  for (int h = 0; h < 32; h++) {
    float a = Ds[r_][h];
    float4 bv = *(const float4*)&Xs[h][j4];
    a0 = fmaf(a, bv.x, a0); a1 = fmaf(a, bv.y, a1);
    a2 = fmaf(a, bv.z, a2); a3 = fmaf(a, bv.w, a3);
  }
  *(float4*)&T1[r_][j4] = make_float4(a0, a1, a2, a3);
  __syncthreads();
  a0 = a1 = a2 = a3 = 0;
#pragma unroll
  for (int w = 0; w < 32; w++) {
    float a = T1[r_][w];
    float4 bv = *(const float4*)&Dt[w][j4];
    a0 = fmaf(a, bv.x, a0); a1 = fmaf(a, bv.y, a1);
    a2 = fmaf(a, bv.z, a2); a3 = fmaf(a, bv.w, a3);
  }
  {
    float4 mv = *(const float4*)(lm + r_ * 32 + j4);
    a0 *= fmaf(gl, mv.x, gh * (1.f - mv.x));
    a1 *= fmaf(gl, mv.y, gh * (1.f - mv.y));
    a2 *= fmaf(gl, mv.z, gh * (1.f - mv.z));
    a3 *= fmaf(gl, mv.w, gh * (1.f - mv.w));
  }
  __syncthreads();
  *(float4*)&Xs[r_][j4] = make_float4(a0, a1, a2, a3);
  __syncthreads();
  a0 = a1 = a2 = a3 = 0;
#pragma unroll
  for (int ii = 0; ii < 32; ii++) {
    float a = Dt[r_][ii];
    float4 bv = *(const float4*)&Xs[ii][j4];
    a0 = fmaf(a, bv.x, a0); a1 = fmaf(a, bv.y, a1);
    a2 = fmaf(a, bv.z, a2); a3 = fmaf(a, bv.w, a3);
  }
  __syncthreads();
  *(float4*)&T1[r_][j4] = make_float4(a0, a1, a2, a3);
  __syncthreads();
  a0 = a1 = a2 = a3 = 0;
#pragma unroll
  for (int jj = 0; jj < 32; jj++) {
    float a = T1[r_][jj];
    float4 bv = *(const float4*)&Ds[jj][j4];
    a0 = fmaf(a, bv.x, a0); a1 = fmaf(a, bv.y, a1);
    a2 = fmaf(a, bv.z, a2); a3 = fmaf(a, bv.w, a3);
  }
  *(float4*)(y + tid * 4) = make_float4(a0, a1, a2, a3);
}

// ---------------- row softmax + emit bf16 hi/lo ----------------
__global__ __launch_bounds__(256) void k_softmax_split(
    const float* __restrict__ sc, u16* __restrict__ ahi, u16* __restrict__ alo) {
  __shared__ float redm[4], reds[4];
  i64 row = blockIdx.x;
  const float* p = sc + row * (i64)Nq;
  int tid = threadIdx.x;
  float4 v = ((const float4*)p)[tid];
  float mx = fmaxf(fmaxf(v.x, v.y), fmaxf(v.z, v.w));
#pragma unroll
  for (int o = 32; o > 0; o >>= 1) mx = fmaxf(mx, __shfl_xor(mx, o, 64));
  if ((tid & 63) == 0) redm[tid >> 6] = mx;
  __syncthreads();
  mx = fmaxf(fmaxf(redm[0], redm[1]), fmaxf(redm[2], redm[3]));
  v.x = expf(v.x - mx); v.y = expf(v.y - mx);
  v.z = expf(v.z - mx); v.w = expf(v.w - mx);
  float s = v.x + v.y + v.z + v.w;
#pragma unroll
  for (int o = 32; o > 0; o >>= 1) s += __shfl_xor(s, o, 64);
  if ((tid & 63) == 0) reds[tid >> 6] = s;
  __syncthreads();
  s = reds[0] + reds[1] + reds[2] + reds[3];
  float inv = 1.0f / s;
  v.x *= inv; v.y *= inv; v.z *= inv; v.w *= inv;
  ushort4 h, l;
  h.x = f2bf(v.x); l.x = f2bf(v.x - bf2f(h.x));
  h.y = f2bf(v.y); l.y = f2bf(v.y - bf2f(h.y));
  h.z = f2bf(v.z); l.z = f2bf(v.z - bf2f(h.z));
  h.w = f2bf(v.w); l.w = f2bf(v.w - bf2f(h.w));
  *(ushort4*)(ahi + row * Nq + tid * 4) = h;
  *(ushort4*)(alo + row * Nq + tid * 4) = l;
}

// ---------------- channel attention MLP ----------------
__global__ __launch_bounds__(512) void k_ca(
    const float* __restrict__ pooled, const float* __restrict__ w1,
    const float* __restrict__ b1, const float* __restrict__ w2,
    const float* __restrict__ b2, float* __restrict__ wt) {
  __shared__ float pl[Cq];
  __shared__ float h[MIDq];
  int b = blockIdx.x, tid = threadIdx.x;
  pl[tid] = pooled[b * Cq + tid];
  __syncthreads();
  if (tid < MIDq) {
    float s = b1[tid];
    const float* wr = w1 + (i64)tid * Cq;
    for (int c = 0; c < Cq; c++) s = fmaf(wr[c], pl[c], s);
    h[tid] = fmaxf(s, 0.f);
  }
  __syncthreads();
  float s = b2[tid];
  const float* wr = w2 + (i64)tid * MIDq;
  for (int m = 0; m < MIDq; m++) s = fmaf(wr[m], h[m], s);
  wt[b * Cq + tid] = 1.0f / (1.0f + expf(-s));
}

// ---------------- final: out = rgb_p + spatial * weight[b,c] ----------------
__global__ __launch_bounds__(256) void k_final(
    const float* __restrict__ rgbp, const float* __restrict__ sp,
    const float* __restrict__ wt, float* __restrict__ out) {
  i64 idx = (i64)blockIdx.x * 256 + threadIdx.x;
  float4 a = ((const float4*)rgbp)[idx];
  float4 s = ((const float4*)sp)[idx];
  float w = wt[idx >> 8];
  float4 r;
  r.x = fmaf(s.x, w, a.x); r.y = fmaf(s.y, w, a.y);
  r.z = fmaf(s.z, w, a.z); r.w = fmaf(s.w, w, a.w);
  ((float4*)out)[idx] = r;
}

extern "C" void kernel_launch(void* const* d_in, const int* in_sizes, int n_in,
                              void* d_out, int out_size, void* d_ws, size_t ws_size,
                              hipStream_t stream) {
  (void)in_sizes; (void)n_in; (void)out_size; (void)ws_size;
  const float* rgb    = (const float*)d_in[0];
  const float* dsm    = (const float*)d_in[1];
  const float* rgb_w  = (const float*)d_in[2];
  const float* rgb_b  = (const float*)d_in[3];
  const float* dsm_w  = (const float*)d_in[4];
  const float* dsm_b  = (const float*)d_in[5];
  const float* gate_w1 = (const float*)d_in[6];
  const float* gate_b1 = (const float*)d_in[7];
  const float* gate_w2 = (const float*)d_in[8];
  const float* gate_b2 = (const float*)d_in[9];
  const float* q_w = (const float*)d_in[10];
  const float* q_b = (const float*)d_in[11];
  const float* k_w = (const float*)d_in[12];
  const float* k_b = (const float*)d_in[13];
  const float* v_w = (const float*)d_in[14];
  const float* v_b = (const float*)d_in[15];
  const float* sp_w = (const float*)d_in[16];
  const float* sp_b = (const float*)d_in[17];
  const float* ca_w1 = (const float*)d_in[18];
  const float* ca_b1 = (const float*)d_in[19];
  const float* ca_w2 = (const float*)d_in[20];
  const float* ca_b2 = (const float*)d_in[21];

  const i64 S  = (i64)Bq * Cq * Nq;      // 8,388,608
  const i64 SU = S;
  const i64 WE = (i64)Cq * Cq;           // 262144
  const i64 XPT = (i64)Bq * XPBq;        // 9,469,952

  float* wsf = (float*)d_ws;
  // fp32 slots (4 x S)
  float* rgbp   = wsf;                   // slot0, live to end
  float* dsmp   = wsf + S;               // slot1 -> scores(lo half) -> xpad
  float* rgbf   = wsf + 2 * S;           // slot2 -> scores(hi half) -> xpad tail
  float* dsmf   = wsf + 3 * S;           // slot3 -> spatial
  float* scores  = dsmp;                 // spans slots 1-2
  float* spatial = dsmf;
  // xpad (conv3 input) overlays the dead scores region after softmax
  u16* XPh = (u16*)dsmp;
  u16* XPl = XPh + XPT;                  // total 75.8 MB < 2S floats
  // small fp32 region (32768 floats)
  float* smallr = wsf + 4 * S;
  float* Dm     = smallr;                // 1024
  float* lm     = smallr + 1024;         // 1024
  float* pooled = smallr + 2048;         // 16384 (2 * B*C)
  float* g_all  = smallr + 18432;        // 64
  float* wt     = smallr + 18496;        // 8192
  // bf16 units
  u16* ub = (u16*)(wsf + 4 * S + 32768);
  u16* U0 = ub;          u16* U1 = ub + SU;
  u16* U2 = ub + 2 * SU;
  u16* U4 = ub + 4 * SU; u16* U5 = ub + 5 * SU;
  // split weights
  u16* wb = ub + 6 * SU;
  u16* rgbw_h = wb;           u16* rgbw_l = wb + WE;
  u16* dsmw_h = wb + 2 * WE;  u16* dsmw_l = wb + 3 * WE;
  u16* qw_h   = wb + 4 * WE;  u16* qw_l   = wb + 5 * WE;
  u16* kw_h   = wb + 6 * WE;  u16* kw_l   = wb + 7 * WE;
  u16* vw_h   = wb + 8 * WE;  u16* vw_l   = wb + 9 * WE;
  u16* w9h    = wb + 10 * WE; u16* w9l    = wb + 19 * WE;

  const i64 sT = (i64)Nq * Cq;       // 524288
  const i64 sS = (i64)Nq * Nq;       // 1048576
  const float rsqc = 0.044194173824159216f;

  k_prep<<<1537, 256, 0, stream>>>(rgb_w, dsm_w, q_w, k_w, v_w, sp_w,
                                   rgbw_h, rgbw_l, dsmw_h, dsmw_l, qw_h, qw_l,
                                   kw_h, kw_l, vw_h, vw_l, w9h, w9l, Dm, lm);

  dim3 gW(Nq / 128, Cq / 128, Bq);   // M=512,N=1024 -> (8,4,16)
  dim3 gQ(Cq / 128, Nq / 128, Bq);   // M=1024,N=512 -> (4,8,16)
  dim3 gS(Nq / 128, Nq / 128, Bq);   // M=N=1024 -> (8,8,16)

  // rgb_p[c][n] = rgb_w x rgb (B transposed+split on the fly)
  k_gemm<<<gW, 256, 0, stream>>>(rgbw_h, rgbw_l, nullptr, 0, 0,
                                 nullptr, nullptr, rgb, 1, sT,
                                 rgb_b, 1, 1.0f, Cq, Nq, Cq,
                                 rgbp, nullptr, nullptr, sT, 0);
  // dsm_p
  k_gemm<<<gW, 256, 0, stream>>>(dsmw_h, dsmw_l, nullptr, 0, 0,
                                 nullptr, nullptr, dsm, 1, sT,
                                 dsm_b, 1, 1.0f, Cq, Nq, Cq,
                                 dsmp, nullptr, nullptr, sT, 0);

  k_pool<<<(2 * Bq * Cq) / 4, 256, 0, stream>>>(rgbp, pooled);
  k_gate<<<32, 128, 0, stream>>>(pooled, gate_w1, gate_b1, gate_w2, gate_b2, g_all);

  k_freq<<<2 * Bq * Cq, 256, 0, stream>>>(rgbp, dsmp, rgbf, dsmf, g_all, g_all + 32, Dm, lm);

  // q_t[n][o] split = rgbf^T x q_w^T
  k_gemm<<<gQ, 256, 0, stream>>>(nullptr, nullptr, rgbf, 1, sT,
                                 qw_h, qw_l, nullptr, 0, 0,
                                 q_b, 2, 1.0f, Nq, Cq, Cq,
                                 nullptr, U4, U5, sT, 1);
  // k_t[n][o] split = dsmf^T x k_w^T
  k_gemm<<<gQ, 256, 0, stream>>>(nullptr, nullptr, dsmf, 1, sT,
                                 kw_h, kw_l, nullptr, 0, 0,
                                 k_b, 2, 1.0f, Nq, Cq, Cq,
                                 nullptr, U0, U1, sT, 1);
  // scores[n][m] fp32 = q_t x k_t^T * 1/sqrt(C)
  k_gemm<<<gS, 256, 0, stream>>>(U4, U5, nullptr, 0, sT,
                                 U0, U1, nullptr, 0, sT,
                                 nullptr, 0, rsqc, Nq, Nq, Cq,
                                 scores, nullptr, nullptr, sS, 0);
  // v[c][m] split = v_w x dsmf -> U4,U5
  k_gemm<<<gW, 256, 0, stream>>>(vw_h, vw_l, nullptr, 0, 0,
                                 nullptr, nullptr, dsmf, 1, sT,
                                 v_b, 1, 1.0f, Cq, Nq, Cq,
                                 nullptr, U4, U5, sT, 1);
  // softmax -> attn hi U0, lo U2 (scores region becomes dead after this)
  k_softmax_split<<<Bq * Nq, 256, 0, stream>>>(scores, U0, U2);
  // zero xpad borders (in the now-dead scores region)
  k_zero_border<<<dim3(132, Bq, 2), 64, 0, stream>>>(XPh);
  // PV: xpad[pr][c] (split) = v x attn^T, written pad-transposed directly
  k_gemm<<<gW, 256, 0, stream>>>(U4, U5, nullptr, 0, sT,
                                 U0, U2, nullptr, 0, sS,
                                 nullptr, 0, 1.0f, Cq, Nq, Nq,
                                 nullptr, XPh, XPl, XPBq, 2);

  // conv3 via MFMA (32x32x16, B-super-tile)
  k_conv3_mfma<<<dim3(Nq / 128, Cq / 128, Bq), 256, 0, stream>>>(
      w9h, w9l, XPh, XPl, sp_b, spatial);

  k_pool<<<(Bq * Cq) / 4, 256, 0, stream>>>(spatial, pooled);
  k_ca<<<Bq, 512, 0, stream>>>(pooled, ca_w1, ca_b1, ca_w2, ca_b2, wt);

  k_final<<<(int)(S / 4 / 256), 256, 0, stream>>>(rgbp, spatial, wt, (float*)d_out);
}

// Round 13
// 724.645 us; speedup vs baseline: 1.0279x; 1.0279x over previous
//
#include <hip/hip_runtime.h>

typedef long long i64;
typedef unsigned int u32;
typedef unsigned short u16;

#define Bq 16
#define Cq 512
#define Hq 32
#define Wq 32
#define Nq 1024
#define MIDq 128
#define XPBq 591872   // 34*34*512 per-batch padded-transposed stride

typedef __attribute__((ext_vector_type(8))) short bf16x8;
typedef __attribute__((ext_vector_type(4))) float f32x4;
typedef __attribute__((ext_vector_type(16))) float f32x16;

// float -> bf16 (RNE) and back
static __device__ __forceinline__ u16 f2bf(float f) {
  u32 u = __float_as_uint(f);
  u = (u + 0x7FFFu + ((u >> 16) & 1u)) >> 16;
  return (u16)u;
}
static __device__ __forceinline__ float bf2f(u16 h) {
  return __uint_as_float(((u32)h) << 16);
}

// ---------------- merged prep: 5 weight splits + 3x3 repack + DCT/mask ----------------
__global__ __launch_bounds__(256) void k_prep(
    const float* __restrict__ rgb_w, const float* __restrict__ dsm_w,
    const float* __restrict__ q_w, const float* __restrict__ k_w,
    const float* __restrict__ v_w, const float* __restrict__ sp_w,
    u16* __restrict__ rw_h, u16* __restrict__ rw_l,
    u16* __restrict__ dw_h, u16* __restrict__ dw_l,
    u16* __restrict__ qw_h, u16* __restrict__ qw_l,
    u16* __restrict__ kw_h, u16* __restrict__ kw_l,
    u16* __restrict__ vw_h, u16* __restrict__ vw_l,
    u16* __restrict__ w9h, u16* __restrict__ w9l,
    float* __restrict__ Dm, float* __restrict__ lm) {
  int blk = blockIdx.x, tid = threadIdx.x;
  if (blk < 1280) {
    int wi = blk >> 8;
    const float* src = wi == 0 ? rgb_w : wi == 1 ? dsm_w : wi == 2 ? q_w : wi == 3 ? k_w : v_w;
    u16* hi = wi == 0 ? rw_h : wi == 1 ? dw_h : wi == 2 ? qw_h : wi == 3 ? kw_h : vw_h;
    u16* lo = wi == 0 ? rw_l : wi == 1 ? dw_l : wi == 2 ? qw_l : wi == 3 ? kw_l : vw_l;
    i64 idx = ((i64)(blk & 255) * 256 + tid) * 4;
    float4 f = *(const float4*)(src + idx);
    ushort4 h, l;
    h.x = f2bf(f.x); l.x = f2bf(f.x - bf2f(h.x));
    h.y = f2bf(f.y); l.y = f2bf(f.y - bf2f(h.y));
    h.z = f2bf(f.z); l.z = f2bf(f.z - bf2f(h.z));
    h.w = f2bf(f.w); l.w = f2bf(f.w - bf2f(h.w));
    *(ushort4*)(hi + idx) = h;
    *(ushort4*)(lo + idx) = l;
  } else if (blk < 1536) {
    int idx = (blk - 1280) * 256 + tid;   // 65536 total
    int o = idx >> 7;
    int c4 = (idx & 127) << 2;
    float vals[4][9];
#pragma unroll
    for (int j = 0; j < 4; j++) {
      const float* wp = sp_w + ((i64)o * Cq + c4 + j) * 9;
#pragma unroll
      for (int t = 0; t < 9; t++) vals[j][t] = wp[t];
    }
#pragma unroll
    for (int t = 0; t < 9; t++) {
      ushort4 h, l;
      h.x = f2bf(vals[0][t]); l.x = f2bf(vals[0][t] - bf2f(h.x));
      h.y = f2bf(vals[1][t]); l.y = f2bf(vals[1][t] - bf2f(h.y));
      h.z = f2bf(vals[2][t]); l.z = f2bf(vals[2][t] - bf2f(h.z));
      h.w = f2bf(vals[3][t]); l.w = f2bf(vals[3][t] - bf2f(h.w));
      i64 od = (i64)t * (Cq * Cq) + (i64)o * Cq + c4;
      *(ushort4*)(w9h + od) = h;
      *(ushort4*)(w9l + od) = l;
    }
  } else {
#pragma unroll
    for (int q4 = 0; q4 < 4; q4++) {
      int t = tid * 4 + q4;          // 0..1023
      int i = t >> 5, j = t & 31;
      float v = cosf(3.14159265358979323846f * (2.0f * j + 1.0f) * (float)i / 64.0f) * 0.25f;
      if (i == 0) v *= 0.7071067811865476f;
      Dm[t] = v;
      float yy = i * (1.0f / 31.0f), xx = j * (1.0f / 31.0f);
      float rr = sqrtf(yy * yy + xx * xx) * 0.7071067811865476f;
      lm[t] = (rr <= 0.35f) ? 1.0f : 0.0f;
    }
  }
}

// ---------------- zero only the 132 border rows of xpad (hi & lo) ----------------
__global__ __launch_bounds__(64) void k_zero_border(u16* __restrict__ xp) {
  int i = blockIdx.x;     // 0..131 border-row index
  int b = blockIdx.y;     // batch
  int arr = blockIdx.z;   // 0 hi, 1 lo
  int pr;
  if (i < 34) pr = i;
  else if (i < 68) pr = 33 * 34 + (i - 34);
  else { int j = i - 68; pr = (1 + (j >> 1)) * 34 + (j & 1) * 33; }
  u16* p = xp + (i64)arr * ((i64)Bq * XPBq) + (i64)b * XPBq + (i64)pr * Cq;
  *(uint4*)(p + threadIdx.x * 8) = (uint4){0u, 0u, 0u, 0u};
}

// ---------------- bf16x3 MFMA GEMM (16x16x32), 512 threads, 8 waves of 64x32 ----------------
// C[b][M][N] = A[b][M][K] * B[b][N][K]^T
// a_mode/b_mode: 0 = pre-split bf16 hi/lo k-contiguous [M|N][K]; 1 = fp32 [K][M|N] transposed+split on the fly.
// bias_mode: 0 none, 1 bias[row], 2 bias[col].
// out_mode: 0 fp32 [M][N]; 1 bf16 hi/lo split [M][N]; 2 bf16 hi/lo pad-transposed xpad layout.
__global__ __launch_bounds__(512) void k_gemm(
    const u16* __restrict__ Ahi, const u16* __restrict__ Alo,
    const float* __restrict__ Af32, int a_mode, i64 sAb,
    const u16* __restrict__ Bhi, const u16* __restrict__ Blo,
    const float* __restrict__ Bf32, int b_mode, i64 sBb,
    const float* __restrict__ bias, int bias_mode, float scale,
    int M, int N, int K,
    float* __restrict__ Cf, u16* __restrict__ Chi, u16* __restrict__ Clo,
    i64 sCb, int out_mode) {
  __shared__ __align__(16) u16 As_h[128][40];
  __shared__ __align__(16) u16 As_l[128][40];
  __shared__ __align__(16) u16 Bs_h[128][40];
  __shared__ __align__(16) u16 Bs_l[128][40];
  int tid = threadIdx.x;
  // XCD-aware bijective block swizzle
  int gx = gridDim.x, gxy = gx * gridDim.y;
  int nwg = gxy * gridDim.z;
  int orig = blockIdx.x + gx * blockIdx.y + gxy * blockIdx.z;
  int wg = (nwg & 7) ? orig : ((orig & 7) * (nwg >> 3) + (orig >> 3));
  int b = wg / gxy;
  int rem = wg - b * gxy;
  int m0 = (rem / gx) << 7;
  int n0 = (rem - (rem / gx) * gx) << 7;
  const u16* pAhi = Ahi + (i64)b * (a_mode ? 0 : sAb);
  const u16* pAlo = Alo + (i64)b * (a_mode ? 0 : sAb);
  const float* pAf = a_mode ? (Af32 + (i64)b * sAb) : nullptr;
  const u16* pBhi = Bhi + (i64)b * (b_mode ? 0 : sBb);
  const u16* pBlo = Blo + (i64)b * (b_mode ? 0 : sBb);
  const float* pBf = b_mode ? (Bf32 + (i64)b * sBb) : nullptr;
  int lane = tid & 63;
  int wid = tid >> 6;              // 0..7
  int wm = (wid & 1) << 6;         // 0 | 64
  int wn = (wid >> 1) << 5;        // 0 | 32 | 64 | 96
  int l15 = lane & 15;
  int g8 = (lane >> 4) << 3;
  f32x4 acc[4][2];
#pragma unroll
  for (int mi = 0; mi < 4; mi++)
#pragma unroll
    for (int nj = 0; nj < 2; nj++)
      acc[mi][nj] = (f32x4){0.f, 0.f, 0.f, 0.f};

  for (int k0 = 0; k0 < K; k0 += 32) {
    // ---- stage A ----
    if (a_mode == 0) {
      int r = tid >> 2, seg = tid & 3;
      *(uint4*)&As_h[r][seg * 8] = *(const uint4*)(pAhi + (i64)(m0 + r) * K + k0 + seg * 8);
      *(uint4*)&As_l[r][seg * 8] = *(const uint4*)(pAlo + (i64)(m0 + r) * K + k0 + seg * 8);
    } else {
      int cs = tid >> 6, ns = tid & 63;   // cs: 4 k-rows; ns: 2 cols
      const float* src = pAf + (i64)(k0 + cs * 4) * M + m0 + ns * 2;
      float2 f[4];
#pragma unroll
      for (int j = 0; j < 4; j++) f[j] = *(const float2*)(src + (i64)j * M);
#pragma unroll
      for (int i = 0; i < 2; i++) {
        union { u16 u[4]; uint2 v; } hh, ll;
#pragma unroll
        for (int j = 0; j < 4; j++) {
          float x = i ? f[j].y : f[j].x;
          u16 h = f2bf(x);
          hh.u[j] = h;
          ll.u[j] = (u16)(__float_as_uint(x - bf2f(h)) >> 16);
        }
        *(uint2*)&As_h[2 * ns + i][cs * 4] = hh.v;
        *(uint2*)&As_l[2 * ns + i][cs * 4] = ll.v;
      }
    }
    // ---- stage B ----
    if (b_mode == 0) {
      int r = tid >> 2, seg = tid & 3;
      *(uint4*)&Bs_h[r][seg * 8] = *(const uint4*)(pBhi + (i64)(n0 + r) * K + k0 + seg * 8);
      *(uint4*)&Bs_l[r][seg * 8] = *(const uint4*)(pBlo + (i64)(n0 + r) * K + k0 + seg * 8);
    } else {
      int cs = tid >> 6, ns = tid & 63;
      const float* src = pBf + (i64)(k0 + cs * 4) * N + n0 + ns * 2;
      float2 f[4];
#pragma unroll
      for (int j = 0; j < 4; j++) f[j] = *(const float2*)(src + (i64)j * N);
#pragma unroll
      for (int i = 0; i < 2; i++) {
        union { u16 u[4]; uint2 v; } hh, ll;
#pragma unroll
        for (int j = 0; j < 4; j++) {
          float x = i ? f[j].y : f[j].x;
          u16 h = f2bf(x);
          hh.u[j] = h;
          ll.u[j] = (u16)(__float_as_uint(x - bf2f(h)) >> 16);
        }
        *(uint2*)&Bs_h[2 * ns + i][cs * 4] = hh.v;
        *(uint2*)&Bs_l[2 * ns + i][cs * 4] = ll.v;
      }
    }
    __syncthreads();
    bf16x8 ah[4], al[4], bh[2], bl[2];
#pragma unroll
    for (int mi = 0; mi < 4; mi++) {
      int row = wm + mi * 16 + l15;
      ah[mi] = *(const bf16x8*)&As_h[row][g8];
      al[mi] = *(const bf16x8*)&As_l[row][g8];
    }
#pragma unroll
    for (int nj = 0; nj < 2; nj++) {
      int row = wn + nj * 16 + l15;
      bh[nj] = *(const bf16x8*)&Bs_h[row][g8];
      bl[nj] = *(const bf16x8*)&Bs_l[row][g8];
    }
#pragma unroll
    for (int mi = 0; mi < 4; mi++)
#pragma unroll
      for (int nj = 0; nj < 2; nj++) {
        acc[mi][nj] = __builtin_amdgcn_mfma_f32_16x16x32_bf16(ah[mi], bh[nj], acc[mi][nj], 0, 0, 0);
        acc[mi][nj] = __builtin_amdgcn_mfma_f32_16x16x32_bf16(ah[mi], bl[nj], acc[mi][nj], 0, 0, 0);
        acc[mi][nj] = __builtin_amdgcn_mfma_f32_16x16x32_bf16(al[mi], bh[nj], acc[mi][nj], 0, 0, 0);
      }
    __syncthreads();
  }

#pragma unroll
  for (int mi = 0; mi < 4; mi++)
#pragma unroll
    for (int nj = 0; nj < 2; nj++) {
      int col_g = n0 + wn + nj * 16 + l15;
      int row_b = m0 + wm + mi * 16 + ((lane >> 4) << 2);
      float v4[4];
#pragma unroll
      for (int r = 0; r < 4; r++) {
        float val = acc[mi][nj][r] * scale;
        if (bias_mode == 1) val += bias[row_b + r];
        else if (bias_mode == 2) val += bias[col_g];
        v4[r] = val;
      }
      if (out_mode == 0) {
#pragma unroll
        for (int r = 0; r < 4; r++)
          Cf[(i64)b * sCb + (i64)(row_b + r) * N + col_g] = v4[r];
      } else if (out_mode == 1) {
#pragma unroll
        for (int r = 0; r < 4; r++) {
          i64 o = (i64)b * sCb + (i64)(row_b + r) * N + col_g;
          u16 h = f2bf(v4[r]);
          Chi[o] = h;
          Clo[o] = f2bf(v4[r] - bf2f(h));
        }
      } else {
        // out_mode 2: pad-transposed xpad write; col_g = pixel n, rows = 4 channels
        int pr = ((col_g >> 5) + 1) * 34 + (col_g & 31) + 1;
        i64 o = (i64)b * sCb + (i64)pr * Cq + row_b;
        ushort4 hh, ll;
        hh.x = f2bf(v4[0]); ll.x = f2bf(v4[0] - bf2f(hh.x));
        hh.y = f2bf(v4[1]); ll.y = f2bf(v4[1] - bf2f(hh.y));
        hh.z = f2bf(v4[2]); ll.z = f2bf(v4[2] - bf2f(hh.z));
        hh.w = f2bf(v4[3]); ll.w = f2bf(v4[3] - bf2f(hh.w));
        *(ushort4*)(Chi + o) = hh;
        *(ushort4*)(Clo + o) = ll;
      }
    }
}

// ---------------- MFMA 3x3 conv (32x32x16), 256 threads, B-super-tile over 9 taps ----------------
__global__ __launch_bounds__(256) void k_conv3_mfma(
    const u16* __restrict__ Wh, const u16* __restrict__ Wl,
    const u16* __restrict__ Xh, const u16* __restrict__ Xl,
    const float* __restrict__ bias, float* __restrict__ out) {
  __shared__ __align__(16) u16 As_h[128][40];
  __shared__ __align__(16) u16 As_l[128][40];
  __shared__ __align__(16) u16 Bs_h[204][40];
  __shared__ __align__(16) u16 Bs_l[204][40];
  int tid = threadIdx.x;
  // XCD-aware bijective block swizzle
  int gx = gridDim.x, gxy = gx * gridDim.y;
  int nwg = gxy * gridDim.z;
  int orig = blockIdx.x + gx * blockIdx.y + gxy * blockIdx.z;
  int wg = (nwg & 7) ? orig : ((orig & 7) * (nwg >> 3) + (orig >> 3));
  int b = wg / gxy;
  int rem = wg - b * gxy;
  int m0 = (rem / gx) << 7;                // out-channel tile
  int n0 = (rem - (rem / gx) * gx) << 7;   // pixel tile (4 image rows)
  int lane = tid & 63;
  int wid = tid >> 6;                      // 0..3
  int wm = (wid & 1) << 6;
  int wn = (wid >> 1) << 6;
  int l31 = lane & 31;
  int kg = (lane >> 5) << 3;
  int yb = n0 >> 5;
  const u16* pXh = Xh + (i64)b * XPBq + (i64)(yb * 34) * Cq;  // 204-row window
  const u16* pXl = Xl + (i64)b * XPBq + (i64)(yb * 34) * Cq;
  int bbase[2];
#pragma unroll
  for (int nj = 0; nj < 2; nj++) {
    int nloc = wn + nj * 32 + l31;        // 0..127
    bbase[nj] = (nloc >> 5) * 34 + (nloc & 31);
  }
  f32x16 acc[2][2];
#pragma unroll
  for (int mi = 0; mi < 2; mi++)
#pragma unroll
    for (int nj = 0; nj < 2; nj++)
      acc[mi][nj] = (f32x16){0.f,0.f,0.f,0.f,0.f,0.f,0.f,0.f,0.f,0.f,0.f,0.f,0.f,0.f,0.f,0.f};

  for (int c0 = 0; c0 < Cq; c0 += 32) {
    // ---- stage B super-tile: 204 rows x 32 ch (hi + lo), once per c0 ----
    for (int e = tid; e < 816; e += 256) {   // 204 rows * 4 uint4
      int row = e >> 2, q = e & 3;
      i64 src = (i64)row * Cq + c0 + q * 8;
      *(uint4*)&Bs_h[row][q * 8] = *(const uint4*)(pXh + src);
      *(uint4*)&Bs_l[row][q * 8] = *(const uint4*)(pXl + src);
    }
    for (int tap = 0; tap < 9; tap++) {
      int doff = (tap / 3) * 34 + (tap % 3);
      // ---- stage A: weights for this (tap, c0), 128 rows x 32 ch ----
      {
        int r = tid >> 1, q0 = (tid & 1) << 1;
        i64 wo = (i64)tap * (Cq * Cq) + (i64)(m0 + r) * Cq + c0;
        *(uint4*)&As_h[r][q0 * 8]       = *(const uint4*)(Wh + wo + q0 * 8);
        *(uint4*)&As_h[r][(q0 + 1) * 8] = *(const uint4*)(Wh + wo + (q0 + 1) * 8);
        *(uint4*)&As_l[r][q0 * 8]       = *(const uint4*)(Wl + wo + q0 * 8);
        *(uint4*)&As_l[r][(q0 + 1) * 8] = *(const uint4*)(Wl + wo + (q0 + 1) * 8);
      }
      __syncthreads();
#pragma unroll
      for (int kstep = 0; kstep < 2; kstep++) {
        int kc = kstep * 16 + kg;
        bf16x8 ah[2], al[2], bh[2], bl[2];
#pragma unroll
        for (int mi = 0; mi < 2; mi++) {
          int row = wm + mi * 32 + l31;
          ah[mi] = *(const bf16x8*)&As_h[row][kc];
          al[mi] = *(const bf16x8*)&As_l[row][kc];
        }
#pragma unroll
        for (int nj = 0; nj < 2; nj++) {
          int row = bbase[nj] + doff;
          bh[nj] = *(const bf16x8*)&Bs_h[row][kc];
          bl[nj] = *(const bf16x8*)&Bs_l[row][kc];
        }
#pragma unroll
        for (int mi = 0; mi < 2; mi++)
#pragma unroll
          for (int nj = 0; nj < 2; nj++) {
            acc[mi][nj] = __builtin_amdgcn_mfma_f32_32x32x16_bf16(ah[mi], bh[nj], acc[mi][nj], 0, 0, 0);
            acc[mi][nj] = __builtin_amdgcn_mfma_f32_32x32x16_bf16(ah[mi], bl[nj], acc[mi][nj], 0, 0, 0);
            acc[mi][nj] = __builtin_amdgcn_mfma_f32_32x32x16_bf16(al[mi], bh[nj], acc[mi][nj], 0, 0, 0);
          }
      }
      __syncthreads();
    }
  }

#pragma unroll
  for (int mi = 0; mi < 2; mi++)
#pragma unroll
    for (int nj = 0; nj < 2; nj++) {
      int col_g = n0 + wn + nj * 32 + l31;
#pragma unroll
      for (int g = 0; g < 4; g++) {
        int row_b = m0 + wm + mi * 32 + g * 8 + ((lane >> 5) << 2);
#pragma unroll
        for (int r = 0; r < 4; r++) {
          float val = acc[mi][nj][g * 4 + r] + bias[row_b + r];
          out[(i64)b * (Cq * Nq) + (i64)(row_b + r) * Nq + col_g] = val;
        }
      }
    }
}

// ---------------- mean over N per (b,c): one wave per row ----------------
__global__ __launch_bounds__(256) void k_pool(const float* __restrict__ x, float* __restrict__ o) {
  int gw = (int)((blockIdx.x * 256 + threadIdx.x) >> 6);
  int ln = threadIdx.x & 63;
  const float* p = x + (i64)gw * Nq;
  float s = 0.f;
#pragma unroll
  for (int it = 0; it < 4; it++) {
    float4 v = *(const float4*)(p + ln * 4 + it * 256);
    s += v.x + v.y + v.z + v.w;
  }
#pragma unroll
  for (int off = 32; off > 0; off >>= 1) s += __shfl_xor(s, off, 64);
  if (ln == 0) o[gw] = s * (1.0f / 1024.0f);
}

// ---------------- gate MLP (32 blocks: 0-15 rgb, 16-31 dsm) ----------------
__global__ __launch_bounds__(128) void k_gate(
    const float* __restrict__ pooled, const float* __restrict__ w1,
    const float* __restrict__ b1, const float* __restrict__ w2,
    const float* __restrict__ b2, float* __restrict__ g) {
  __shared__ float pl[Cq];
  __shared__ float h[MIDq];
  int bb = blockIdx.x, tid = threadIdx.x;
  for (int c = tid; c < Cq; c += 128) pl[c] = pooled[bb * Cq + c];
  __syncthreads();
  float s = b1[tid];
  const float* wr = w1 + (i64)tid * Cq;
  for (int c = 0; c < Cq; c++) s = fmaf(wr[c], pl[c], s);
  h[tid] = fmaxf(s, 0.f);
  __syncthreads();
  if (tid < 2) {
    float t = b2[tid];
    const float* w2r = w2 + tid * MIDq;
    for (int m = 0; m < MIDq; m++) t = fmaf(w2r[m], h[m], t);
    g[bb * 2 + tid] = 1.0f / (1.0f + expf(-t));
  }
}

// ---------------- fused DCT -> gate -> iDCT per (b,c) 32x32 image ----------------
__global__ __launch_bounds__(256) void k_freq(
    const float* __restrict__ xr, const float* __restrict__ xd,
    float* __restrict__ yr, float* __restrict__ yd,
    const float* __restrict__ g_r, const float* __restrict__ g_d,
    const float* __restrict__ Dm, const float* __restrict__ lm) {
  __shared__ float Ds[32][36], Dt[32][36], Xs[32][36], T1[32][36];
  int bid = blockIdx.x;
  const float* x; float* y; const float* g;
  if (bid < Bq * Cq) {
    x = xr + (i64)bid * Nq; y = yr + (i64)bid * Nq; g = g_r + (bid >> 9) * 2;
  } else {
    int id = bid - Bq * Cq;
    x = xd + (i64)id * Nq; y = yd + (i64)id * Nq; g = g_d + (id >> 9) * 2;
  }
  int tid = threadIdx.x;
  int r_ = tid >> 3, j4 = (tid & 7) << 2;
  {
    float4 dv = *(const float4*)(Dm + tid * 4);
    *(float4*)&Ds[r_][j4] = dv;
    Dt[j4 + 0][r_] = dv.x; Dt[j4 + 1][r_] = dv.y;
    Dt[j4 + 2][r_] = dv.z; Dt[j4 + 3][r_] = dv.w;
    *(float4*)&Xs[r_][j4] = *(const float4*)(x + tid * 4);
  }
  float gl = g[0], gh = g[1];
  __syncthreads();
  float a0 = 0, a1 = 0, a2 = 0, a3 = 0;
#pragma unroll
  for (int h = 0; h < 32; h++) {
    float a = Ds[r_][h];
    float4 bv = *(const float4*)&Xs[h][j4];
    a0 = fmaf(a, bv.x, a0); a1 = fmaf(a, bv.y, a1);
    a2 = fmaf(a, bv.z, a2); a3 = fmaf(a, bv.w, a3);
  }
  *(float4*)&T1[r_][j4] = make_float4(a0, a1, a2, a3);
  __syncthreads();
  a0 = a1 = a2 = a3 = 0;
#pragma unroll
  for (int w = 0; w < 32; w++) {
    float a = T1[r_][w];
    float4 bv = *(const float4*)&Dt[w][j4];
    a0 = fmaf(a, bv.x, a0); a1 = fmaf(a, bv.y, a1);
    a2 = fmaf(a, bv.z, a2); a3 = fmaf(a, bv.w, a3);
  }
  {
    float4 mv = *(const float4*)(lm + r_ * 32 + j4);
    a0 *= fmaf(gl, mv.x, gh * (1.f - mv.x));
    a1 *= fmaf(gl, mv.y, gh * (1.f - mv.y));
    a2 *= fmaf(gl, mv.z, gh * (1.f - mv.z));
    a3 *= fmaf(gl, mv.w, gh * (1.f - mv.w));
  }
  __syncthreads();
  *(float4*)&Xs[r_][j4] = make_float4(a0, a1, a2, a3);
  __syncthreads();
  a0 = a1 = a2 = a3 = 0;
#pragma unroll
  for (int ii = 0; ii < 32; ii++) {
    float a = Dt[r_][ii];
    float4 bv = *(const float4*)&Xs[ii][j4];
    a0 = fmaf(a, bv.x, a0); a1 = fmaf(a, bv.y, a1);
    a2 = fmaf(a, bv.z, a2); a3 = fmaf(a, bv.w, a3);
  }
  __syncthreads();
  *(float4*)&T1[r_][j4] = make_float4(a0, a1, a2, a3);
  __syncthreads();
  a0 = a1 = a2 = a3 = 0;
#pragma unroll
  for (int jj = 0; jj < 32; jj++) {
    float a = T1[r_][jj];
    float4 bv = *(const float4*)&Ds[jj][j4];
    a0 = fmaf(a, bv.x, a0); a1 = fmaf(a, bv.y, a1);
    a2 = fmaf(a, bv.z, a2); a3 = fmaf(a, bv.w, a3);
  }
  *(float4*)(y + tid * 4) = make_float4(a0, a1, a2, a3);
}

// ---------------- row softmax + emit bf16 hi/lo ----------------
__global__ __launch_bounds__(256) void k_softmax_split(
    const float* __restrict__ sc, u16* __restrict__ ahi, u16* __restrict__ alo) {
  __shared__ float redm[4], reds[4];
  i64 row = blockIdx.x;
  const float* p = sc + row * (i64)Nq;
  int tid = threadIdx.x;
  float4 v = ((const float4*)p)[tid];
  float mx = fmaxf(fmaxf(v.x, v.y), fmaxf(v.z, v.w));
#pragma unroll
  for (int o = 32; o > 0; o >>= 1) mx = fmaxf(mx, __shfl_xor(mx, o, 64));
  if ((tid & 63) == 0) redm[tid >> 6] = mx;
  __syncthreads();
  mx = fmaxf(fmaxf(redm[0], redm[1]), fmaxf(redm[2], redm[3]));
  v.x = expf(v.x - mx); v.y = expf(v.y - mx);
  v.z = expf(v.z - mx); v.w = expf(v.w - mx);
  float s = v.x + v.y + v.z + v.w;
#pragma unroll
  for (int o = 32; o > 0; o >>= 1) s += __shfl_xor(s, o, 64);
  if ((tid & 63) == 0) reds[tid >> 6] = s;
  __syncthreads();
  s = reds[0] + reds[1] + reds[2] + reds[3];
  float inv = 1.0f / s;
  v.x *= inv; v.y *= inv; v.z *= inv; v.w *= inv;
  ushort4 h, l;
  h.x = f2bf(v.x); l.x = f2bf(v.x - bf2f(h.x));
  h.y = f2bf(v.y); l.y = f2bf(v.y - bf2f(h.y));
  h.z = f2bf(v.z); l.z = f2bf(v.z - bf2f(h.z));
  h.w = f2bf(v.w); l.w = f2bf(v.w - bf2f(h.w));
  *(ushort4*)(ahi + row * Nq + tid * 4) = h;
  *(ushort4*)(alo + row * Nq + tid * 4) = l;
}

// ---------------- channel attention MLP ----------------
__global__ __launch_bounds__(512) void k_ca(
    const float* __restrict__ pooled, const float* __restrict__ w1,
    const float* __restrict__ b1, const float* __restrict__ w2,
    const float* __restrict__ b2, float* __restrict__ wt) {
  __shared__ float pl[Cq];
  __shared__ float h[MIDq];
  int b = blockIdx.x, tid = threadIdx.x;
  pl[tid] = pooled[b * Cq + tid];
  __syncthreads();
  if (tid < MIDq) {
    float s = b1[tid];
    const float* wr = w1 + (i64)tid * Cq;
    for (int c = 0; c < Cq; c++) s = fmaf(wr[c], pl[c], s);
    h[tid] = fmaxf(s, 0.f);
  }
  __syncthreads();
  float s = b2[tid];
  const float* wr = w2 + (i64)tid * MIDq;
  for (int m = 0; m < MIDq; m++) s = fmaf(wr[m], h[m], s);
  wt[b * Cq + tid] = 1.0f / (1.0f + expf(-s));
}

// ---------------- final: out = rgb_p + spatial * weight[b,c] ----------------
__global__ __launch_bounds__(256) void k_final(
    const float* __restrict__ rgbp, const float* __restrict__ sp,
    const float* __restrict__ wt, float* __restrict__ out) {
  i64 idx = (i64)blockIdx.x * 256 + threadIdx.x;
  float4 a = ((const float4*)rgbp)[idx];
  float4 s = ((const float4*)sp)[idx];
  float w = wt[idx >> 8];
  float4 r;
  r.x = fmaf(s.x, w, a.x); r.y = fmaf(s.y, w, a.y);
  r.z = fmaf(s.z, w, a.z); r.w = fmaf(s.w, w, a.w);
  ((float4*)out)[idx] = r;
}

extern "C" void kernel_launch(void* const* d_in, const int* in_sizes, int n_in,
                              void* d_out, int out_size, void* d_ws, size_t ws_size,
                              hipStream_t stream) {
  (void)in_sizes; (void)n_in; (void)out_size; (void)ws_size;
  const float* rgb    = (const float*)d_in[0];
  const float* dsm    = (const float*)d_in[1];
  const float* rgb_w  = (const float*)d_in[2];
  const float* rgb_b  = (const float*)d_in[3];
  const float* dsm_w  = (const float*)d_in[4];
  const float* dsm_b  = (const float*)d_in[5];
  const float* gate_w1 = (const float*)d_in[6];
  const float* gate_b1 = (const float*)d_in[7];
  const float* gate_w2 = (const float*)d_in[8];
  const float* gate_b2 = (const float*)d_in[9];
  const float* q_w = (const float*)d_in[10];
  const float* q_b = (const float*)d_in[11];
  const float* k_w = (const float*)d_in[12];
  const float* k_b = (const float*)d_in[13];
  const float* v_w = (const float*)d_in[14];
  const float* v_b = (const float*)d_in[15];
  const float* sp_w = (const float*)d_in[16];
  const float* sp_b = (const float*)d_in[17];
  const float* ca_w1 = (const float*)d_in[18];
  const float* ca_b1 = (const float*)d_in[19];
  const float* ca_w2 = (const float*)d_in[20];
  const float* ca_b2 = (const float*)d_in[21];

  const i64 S  = (i64)Bq * Cq * Nq;      // 8,388,608
  const i64 SU = S;
  const i64 WE = (i64)Cq * Cq;           // 262144
  const i64 XPT = (i64)Bq * XPBq;        // 9,469,952

  float* wsf = (float*)d_ws;
  // fp32 slots (4 x S)
  float* rgbp   = wsf;                   // slot0, live to end
  float* dsmp   = wsf + S;               // slot1 -> scores(lo half) -> xpad
  float* rgbf   = wsf + 2 * S;           // slot2 -> scores(hi half) -> xpad tail
  float* dsmf   = wsf + 3 * S;           // slot3 -> spatial
  float* scores  = dsmp;                 // spans slots 1-2
  float* spatial = dsmf;
  // xpad (conv3 input) overlays the dead scores region after softmax
  u16* XPh = (u16*)dsmp;
  u16* XPl = XPh + XPT;                  // total 75.8 MB < 2S floats
  // small fp32 region (32768 floats)
  float* smallr = wsf + 4 * S;
  float* Dm     = smallr;                // 1024
  float* lm     = smallr + 1024;         // 1024
  float* pooled = smallr + 2048;         // 16384 (2 * B*C)
  float* g_all  = smallr + 18432;        // 64
  float* wt     = smallr + 18496;        // 8192
  // bf16 units
  u16* ub = (u16*)(wsf + 4 * S + 32768);
  u16* U0 = ub;          u16* U1 = ub + SU;
  u16* U2 = ub + 2 * SU;
  u16* U4 = ub + 4 * SU; u16* U5 = ub + 5 * SU;
  // split weights
  u16* wb = ub + 6 * SU;
  u16* rgbw_h = wb;           u16* rgbw_l = wb + WE;
  u16* dsmw_h = wb + 2 * WE;  u16* dsmw_l = wb + 3 * WE;
  u16* qw_h   = wb + 4 * WE;  u16* qw_l   = wb + 5 * WE;
  u16* kw_h   = wb + 6 * WE;  u16* kw_l   = wb + 7 * WE;
  u16* vw_h   = wb + 8 * WE;  u16* vw_l   = wb + 9 * WE;
  u16* w9h    = wb + 10 * WE; u16* w9l    = wb + 19 * WE;

  const i64 sT = (i64)Nq * Cq;       // 524288
  const i64 sS = (i64)Nq * Nq;       // 1048576
  const float rsqc = 0.044194173824159216f;

  k_prep<<<1537, 256, 0, stream>>>(rgb_w, dsm_w, q_w, k_w, v_w, sp_w,
                                   rgbw_h, rgbw_l, dsmw_h, dsmw_l, qw_h, qw_l,
                                   kw_h, kw_l, vw_h, vw_l, w9h, w9l, Dm, lm);

  dim3 gW(Nq / 128, Cq / 128, Bq);   // M=512,N=1024 -> (8,4,16)
  dim3 gQ(Cq / 128, Nq / 128, Bq);   // M=1024,N=512 -> (4,8,16)
  dim3 gS(Nq / 128, Nq / 128, Bq);   // M=N=1024 -> (8,8,16)

  // rgb_p[c][n] = rgb_w x rgb (B transposed+split on the fly)
  k_gemm<<<gW, 512, 0, stream>>>(rgbw_h, rgbw_l, nullptr, 0, 0,
                                 nullptr, nullptr, rgb, 1, sT,
                                 rgb_b, 1, 1.0f, Cq, Nq, Cq,
                                 rgbp, nullptr, nullptr, sT, 0);
  // dsm_p
  k_gemm<<<gW, 512, 0, stream>>>(dsmw_h, dsmw_l, nullptr, 0, 0,
                                 nullptr, nullptr, dsm, 1, sT,
                                 dsm_b, 1, 1.0f, Cq, Nq, Cq,
                                 dsmp, nullptr, nullptr, sT, 0);

  k_pool<<<(2 * Bq * Cq) / 4, 256, 0, stream>>>(rgbp, pooled);
  k_gate<<<32, 128, 0, stream>>>(pooled, gate_w1, gate_b1, gate_w2, gate_b2, g_all);

  k_freq<<<2 * Bq * Cq, 256, 0, stream>>>(rgbp, dsmp, rgbf, dsmf, g_all, g_all + 32, Dm, lm);

  // q_t[n][o] split = rgbf^T x q_w^T
  k_gemm<<<gQ, 512, 0, stream>>>(nullptr, nullptr, rgbf, 1, sT,
                                 qw_h, qw_l, nullptr, 0, 0,
                                 q_b, 2, 1.0f, Nq, Cq, Cq,
                                 nullptr, U4, U5, sT, 1);
  // k_t[n][o] split = dsmf^T x k_w^T
  k_gemm<<<gQ, 512, 0, stream>>>(nullptr, nullptr, dsmf, 1, sT,
                                 kw_h, kw_l, nullptr, 0, 0,
                                 k_b, 2, 1.0f, Nq, Cq, Cq,
                                 nullptr, U0, U1, sT, 1);
  // scores[n][m] fp32 = q_t x k_t^T * 1/sqrt(C)
  k_gemm<<<gS, 512, 0, stream>>>(U4, U5, nullptr, 0, sT,
                                 U0, U1, nullptr, 0, sT,
                                 nullptr, 0, rsqc, Nq, Nq, Cq,
                                 scores, nullptr, nullptr, sS, 0);
  // v[c][m] split = v_w x dsmf -> U4,U5
  k_gemm<<<gW, 512, 0, stream>>>(vw_h, vw_l, nullptr, 0, 0,
                                 nullptr, nullptr, dsmf, 1, sT,
                                 v_b, 1, 1.0f, Cq, Nq, Cq,
                                 nullptr, U4, U5, sT, 1);
  // softmax -> attn hi U0, lo U2 (scores region becomes dead after this)
  k_softmax_split<<<Bq * Nq, 256, 0, stream>>>(scores, U0, U2);
  // zero xpad borders (in the now-dead scores region)
  k_zero_border<<<dim3(132, Bq, 2), 64, 0, stream>>>(XPh);
  // PV: xpad[pr][c] (split) = v x attn^T, written pad-transposed directly
  k_gemm<<<gW, 512, 0, stream>>>(U4, U5, nullptr, 0, sT,
                                 U0, U2, nullptr, 0, sS,
                                 nullptr, 0, 1.0f, Cq, Nq, Nq,
                                 nullptr, XPh, XPl, XPBq, 2);

  // conv3 via MFMA (32x32x16, 256 threads, B-super-tile)
  k_conv3_mfma<<<dim3(Nq / 128, Cq / 128, Bq), 256, 0, stream>>>(
      w9h, w9l, XPh, XPl, sp_b, spatial);

  k_pool<<<(Bq * Cq) / 4, 256, 0, stream>>>(spatial, pooled);
  k_ca<<<Bq, 512, 0, stream>>>(pooled, ca_w1, ca_b1, ca_w2, ca_b2, wt);

  k_final<<<(int)(S / 4 / 256), 256, 0, stream>>>(rgbp, spatial, wt, (float*)d_out);
}

// Round 14
// 717.919 us; speedup vs baseline: 1.0376x; 1.0094x over previous
//
#include <hip/hip_runtime.h>

typedef long long i64;
typedef unsigned int u32;
typedef unsigned short u16;

#define Bq 16
#define Cq 512
#define Hq 32
#define Wq 32
#define Nq 1024
#define MIDq 128
#define XPBq 591872   // 34*34*512 per-batch padded-transposed stride

typedef __attribute__((ext_vector_type(8))) short bf16x8;
typedef __attribute__((ext_vector_type(4))) float f32x4;
typedef __attribute__((ext_vector_type(16))) float f32x16;

// float -> bf16 (RNE) and back
static __device__ __forceinline__ u16 f2bf(float f) {
  u32 u = __float_as_uint(f);
  u = (u + 0x7FFFu + ((u >> 16) & 1u)) >> 16;
  return (u16)u;
}
static __device__ __forceinline__ float bf2f(u16 h) {
  return __uint_as_float(((u32)h) << 16);
}

// ---------------- merged prep: 5 weight splits + 3x3 repack + DCT/mask ----------------
__global__ __launch_bounds__(256) void k_prep(
    const float* __restrict__ rgb_w, const float* __restrict__ dsm_w,
    const float* __restrict__ q_w, const float* __restrict__ k_w,
    const float* __restrict__ v_w, const float* __restrict__ sp_w,
    u16* __restrict__ rw_h, u16* __restrict__ rw_l,
    u16* __restrict__ dw_h, u16* __restrict__ dw_l,
    u16* __restrict__ qw_h, u16* __restrict__ qw_l,
    u16* __restrict__ kw_h, u16* __restrict__ kw_l,
    u16* __restrict__ vw_h, u16* __restrict__ vw_l,
    u16* __restrict__ w9h, u16* __restrict__ w9l,
    float* __restrict__ Dm, float* __restrict__ lm) {
  int blk = blockIdx.x, tid = threadIdx.x;
  if (blk < 1280) {
    int wi = blk >> 8;
    const float* src = wi == 0 ? rgb_w : wi == 1 ? dsm_w : wi == 2 ? q_w : wi == 3 ? k_w : v_w;
    u16* hi = wi == 0 ? rw_h : wi == 1 ? dw_h : wi == 2 ? qw_h : wi == 3 ? kw_h : vw_h;
    u16* lo = wi == 0 ? rw_l : wi == 1 ? dw_l : wi == 2 ? qw_l : wi == 3 ? kw_l : vw_l;
    i64 idx = ((i64)(blk & 255) * 256 + tid) * 4;
    float4 f = *(const float4*)(src + idx);
    ushort4 h, l;
    h.x = f2bf(f.x); l.x = f2bf(f.x - bf2f(h.x));
    h.y = f2bf(f.y); l.y = f2bf(f.y - bf2f(h.y));
    h.z = f2bf(f.z); l.z = f2bf(f.z - bf2f(h.z));
    h.w = f2bf(f.w); l.w = f2bf(f.w - bf2f(h.w));
    *(ushort4*)(hi + idx) = h;
    *(ushort4*)(lo + idx) = l;
  } else if (blk < 1536) {
    int idx = (blk - 1280) * 256 + tid;   // 65536 total
    int o = idx >> 7;
    int c4 = (idx & 127) << 2;
    float vals[4][9];
#pragma unroll
    for (int j = 0; j < 4; j++) {
      const float* wp = sp_w + ((i64)o * Cq + c4 + j) * 9;
#pragma unroll
      for (int t = 0; t < 9; t++) vals[j][t] = wp[t];
    }
#pragma unroll
    for (int t = 0; t < 9; t++) {
      ushort4 h, l;
      h.x = f2bf(vals[0][t]); l.x = f2bf(vals[0][t] - bf2f(h.x));
      h.y = f2bf(vals[1][t]); l.y = f2bf(vals[1][t] - bf2f(h.y));
      h.z = f2bf(vals[2][t]); l.z = f2bf(vals[2][t] - bf2f(h.z));
      h.w = f2bf(vals[3][t]); l.w = f2bf(vals[3][t] - bf2f(h.w));
      i64 od = (i64)t * (Cq * Cq) + (i64)o * Cq + c4;
      *(ushort4*)(w9h + od) = h;
      *(ushort4*)(w9l + od) = l;
    }
  } else {
#pragma unroll
    for (int q4 = 0; q4 < 4; q4++) {
      int t = tid * 4 + q4;          // 0..1023
      int i = t >> 5, j = t & 31;
      float v = cosf(3.14159265358979323846f * (2.0f * j + 1.0f) * (float)i / 64.0f) * 0.25f;
      if (i == 0) v *= 0.7071067811865476f;
      Dm[t] = v;
      float yy = i * (1.0f / 31.0f), xx = j * (1.0f / 31.0f);
      float rr = sqrtf(yy * yy + xx * xx) * 0.7071067811865476f;
      lm[t] = (rr <= 0.35f) ? 1.0f : 0.0f;
    }
  }
}

// ---------------- zero only the 132 border rows of xpad (hi & lo) ----------------
__global__ __launch_bounds__(64) void k_zero_border(u16* __restrict__ xp) {
  int i = blockIdx.x;     // 0..131 border-row index
  int b = blockIdx.y;     // batch
  int arr = blockIdx.z;   // 0 hi, 1 lo
  int pr;
  if (i < 34) pr = i;
  else if (i < 68) pr = 33 * 34 + (i - 34);
  else { int j = i - 68; pr = (1 + (j >> 1)) * 34 + (j & 1) * 33; }
  u16* p = xp + (i64)arr * ((i64)Bq * XPBq) + (i64)b * XPBq + (i64)pr * Cq;
  *(uint4*)(p + threadIdx.x * 8) = (uint4){0u, 0u, 0u, 0u};
}

// ---------------- bf16x3 MFMA GEMM (16x16x32), 512 threads, 8 waves of 64x32 ----------------
// C[b][M][N] = A[b][M][K] * B[b][N][K]^T
// Supports TWO independent problem sets in one launch: deswizzled y-tile >= ySplit selects set 2
// (same M,N,K, modes, strides; different pointers). Enables concurrent independent GEMMs.
// a_mode/b_mode: 0 = pre-split bf16 hi/lo k-contiguous [M|N][K]; 1 = fp32 [K][M|N] transposed+split.
// bias_mode: 0 none, 1 bias[row], 2 bias[col].
// out_mode: 0 fp32 [M][N]; 1 bf16 hi/lo split [M][N]; 2 bf16 hi/lo pad-transposed xpad layout.
__global__ __launch_bounds__(512) void k_gemm(
    const u16* __restrict__ Ahi, const u16* __restrict__ Alo,
    const float* __restrict__ Af32, int a_mode, i64 sAb,
    const u16* __restrict__ Bhi, const u16* __restrict__ Blo,
    const float* __restrict__ Bf32, int b_mode, i64 sBb,
    const float* __restrict__ bias, int bias_mode, float scale,
    int M, int N, int K,
    float* __restrict__ Cf, u16* __restrict__ Chi, u16* __restrict__ Clo,
    i64 sCb, int out_mode,
    int ySplit,
    const u16* __restrict__ Ahi2, const u16* __restrict__ Alo2,
    const float* __restrict__ Af2,
    const u16* __restrict__ Bhi2, const u16* __restrict__ Blo2,
    const float* __restrict__ Bf2,
    const float* __restrict__ bias2,
    float* __restrict__ Cf2, u16* __restrict__ Chi2, u16* __restrict__ Clo2) {
  __shared__ __align__(16) u16 As_h[128][40];
  __shared__ __align__(16) u16 As_l[128][40];
  __shared__ __align__(16) u16 Bs_h[128][40];
  __shared__ __align__(16) u16 Bs_l[128][40];
  int tid = threadIdx.x;
  // XCD-aware bijective block swizzle
  int gx = gridDim.x, gxy = gx * gridDim.y;
  int nwg = gxy * gridDim.z;
  int orig = blockIdx.x + gx * blockIdx.y + gxy * blockIdx.z;
  int wg = (nwg & 7) ? orig : ((orig & 7) * (nwg >> 3) + (orig >> 3));
  int b = wg / gxy;
  int rem = wg - b * gxy;
  int yy = rem / gx;
  int xx = rem - yy * gx;
  if (yy >= ySplit) {
    yy -= ySplit;
    Ahi = Ahi2; Alo = Alo2; Af32 = Af2;
    Bhi = Bhi2; Blo = Blo2; Bf32 = Bf2;
    bias = bias2; Cf = Cf2; Chi = Chi2; Clo = Clo2;
  }
  int m0 = yy << 7;
  int n0 = xx << 7;
  const u16* pAhi = Ahi + (i64)b * (a_mode ? 0 : sAb);
  const u16* pAlo = Alo + (i64)b * (a_mode ? 0 : sAb);
  const float* pAf = a_mode ? (Af32 + (i64)b * sAb) : nullptr;
  const u16* pBhi = Bhi + (i64)b * (b_mode ? 0 : sBb);
  const u16* pBlo = Blo + (i64)b * (b_mode ? 0 : sBb);
  const float* pBf = b_mode ? (Bf32 + (i64)b * sBb) : nullptr;
  int lane = tid & 63;
  int wid = tid >> 6;              // 0..7
  int wm = (wid & 1) << 6;         // 0 | 64
  int wn = (wid >> 1) << 5;        // 0 | 32 | 64 | 96
  int l15 = lane & 15;
  int g8 = (lane >> 4) << 3;
  f32x4 acc[4][2];
#pragma unroll
  for (int mi = 0; mi < 4; mi++)
#pragma unroll
    for (int nj = 0; nj < 2; nj++)
      acc[mi][nj] = (f32x4){0.f, 0.f, 0.f, 0.f};

  for (int k0 = 0; k0 < K; k0 += 32) {
    // ---- stage A ----
    if (a_mode == 0) {
      int r = tid >> 2, seg = tid & 3;
      *(uint4*)&As_h[r][seg * 8] = *(const uint4*)(pAhi + (i64)(m0 + r) * K + k0 + seg * 8);
      *(uint4*)&As_l[r][seg * 8] = *(const uint4*)(pAlo + (i64)(m0 + r) * K + k0 + seg * 8);
    } else {
      int cs = tid >> 6, ns = tid & 63;   // cs: 4 k-rows; ns: 2 cols
      const float* src = pAf + (i64)(k0 + cs * 4) * M + m0 + ns * 2;
      float2 f[4];
#pragma unroll
      for (int j = 0; j < 4; j++) f[j] = *(const float2*)(src + (i64)j * M);
#pragma unroll
      for (int i = 0; i < 2; i++) {
        union { u16 u[4]; uint2 v; } hh, ll;
#pragma unroll
        for (int j = 0; j < 4; j++) {
          float x = i ? f[j].y : f[j].x;
          u16 h = f2bf(x);
          hh.u[j] = h;
          ll.u[j] = (u16)(__float_as_uint(x - bf2f(h)) >> 16);
        }
        *(uint2*)&As_h[2 * ns + i][cs * 4] = hh.v;
        *(uint2*)&As_l[2 * ns + i][cs * 4] = ll.v;
      }
    }
    // ---- stage B ----
    if (b_mode == 0) {
      int r = tid >> 2, seg = tid & 3;
      *(uint4*)&Bs_h[r][seg * 8] = *(const uint4*)(pBhi + (i64)(n0 + r) * K + k0 + seg * 8);
      *(uint4*)&Bs_l[r][seg * 8] = *(const uint4*)(pBlo + (i64)(n0 + r) * K + k0 + seg * 8);
    } else {
      int cs = tid >> 6, ns = tid & 63;
      const float* src = pBf + (i64)(k0 + cs * 4) * N + n0 + ns * 2;
      float2 f[4];
#pragma unroll
      for (int j = 0; j < 4; j++) f[j] = *(const float2*)(src + (i64)j * N);
#pragma unroll
      for (int i = 0; i < 2; i++) {
        union { u16 u[4]; uint2 v; } hh, ll;
#pragma unroll
        for (int j = 0; j < 4; j++) {
          float x = i ? f[j].y : f[j].x;
          u16 h = f2bf(x);
          hh.u[j] = h;
          ll.u[j] = (u16)(__float_as_uint(x - bf2f(h)) >> 16);
        }
        *(uint2*)&Bs_h[2 * ns + i][cs * 4] = hh.v;
        *(uint2*)&Bs_l[2 * ns + i][cs * 4] = ll.v;
      }
    }
    __syncthreads();
    bf16x8 ah[4], al[4], bh[2], bl[2];
#pragma unroll
    for (int mi = 0; mi < 4; mi++) {
      int row = wm + mi * 16 + l15;
      ah[mi] = *(const bf16x8*)&As_h[row][g8];
      al[mi] = *(const bf16x8*)&As_l[row][g8];
    }
#pragma unroll
    for (int nj = 0; nj < 2; nj++) {
      int row = wn + nj * 16 + l15;
      bh[nj] = *(const bf16x8*)&Bs_h[row][g8];
      bl[nj] = *(const bf16x8*)&Bs_l[row][g8];
    }
#pragma unroll
    for (int mi = 0; mi < 4; mi++)
#pragma unroll
      for (int nj = 0; nj < 2; nj++) {
        acc[mi][nj] = __builtin_amdgcn_mfma_f32_16x16x32_bf16(ah[mi], bh[nj], acc[mi][nj], 0, 0, 0);
        acc[mi][nj] = __builtin_amdgcn_mfma_f32_16x16x32_bf16(ah[mi], bl[nj], acc[mi][nj], 0, 0, 0);
        acc[mi][nj] = __builtin_amdgcn_mfma_f32_16x16x32_bf16(al[mi], bh[nj], acc[mi][nj], 0, 0, 0);
      }
    __syncthreads();
  }

#pragma unroll
  for (int mi = 0; mi < 4; mi++)
#pragma unroll
    for (int nj = 0; nj < 2; nj++) {
      int col_g = n0 + wn + nj * 16 + l15;
      int row_b = m0 + wm + mi * 16 + ((lane >> 4) << 2);
      float v4[4];
#pragma unroll
      for (int r = 0; r < 4; r++) {
        float val = acc[mi][nj][r] * scale;
        if (bias_mode == 1) val += bias[row_b + r];
        else if (bias_mode == 2) val += bias[col_g];
        v4[r] = val;
      }
      if (out_mode == 0) {
#pragma unroll
        for (int r = 0; r < 4; r++)
          Cf[(i64)b * sCb + (i64)(row_b + r) * N + col_g] = v4[r];
      } else if (out_mode == 1) {
#pragma unroll
        for (int r = 0; r < 4; r++) {
          i64 o = (i64)b * sCb + (i64)(row_b + r) * N + col_g;
          u16 h = f2bf(v4[r]);
          Chi[o] = h;
          Clo[o] = f2bf(v4[r] - bf2f(h));
        }
      } else {
        // out_mode 2: pad-transposed xpad write; col_g = pixel n, rows = 4 channels
        int pr = ((col_g >> 5) + 1) * 34 + (col_g & 31) + 1;
        i64 o = (i64)b * sCb + (i64)pr * Cq + row_b;
        ushort4 hh, ll;
        hh.x = f2bf(v4[0]); ll.x = f2bf(v4[0] - bf2f(hh.x));
        hh.y = f2bf(v4[1]); ll.y = f2bf(v4[1] - bf2f(hh.y));
        hh.z = f2bf(v4[2]); ll.z = f2bf(v4[2] - bf2f(hh.z));
        hh.w = f2bf(v4[3]); ll.w = f2bf(v4[3] - bf2f(hh.w));
        *(ushort4*)(Chi + o) = hh;
        *(ushort4*)(Clo + o) = ll;
      }
    }
}

// ---------------- MFMA 3x3 conv (32x32x16), 256 threads, B-super-tile over 9 taps ----------------
__global__ __launch_bounds__(256) void k_conv3_mfma(
    const u16* __restrict__ Wh, const u16* __restrict__ Wl,
    const u16* __restrict__ Xh, const u16* __restrict__ Xl,
    const float* __restrict__ bias, float* __restrict__ out) {
  __shared__ __align__(16) u16 As_h[128][40];
  __shared__ __align__(16) u16 As_l[128][40];
  __shared__ __align__(16) u16 Bs_h[204][40];
  __shared__ __align__(16) u16 Bs_l[204][40];
  int tid = threadIdx.x;
  // XCD-aware bijective block swizzle
  int gx = gridDim.x, gxy = gx * gridDim.y;
  int nwg = gxy * gridDim.z;
  int orig = blockIdx.x + gx * blockIdx.y + gxy * blockIdx.z;
  int wg = (nwg & 7) ? orig : ((orig & 7) * (nwg >> 3) + (orig >> 3));
  int b = wg / gxy;
  int rem = wg - b * gxy;
  int m0 = (rem / gx) << 7;                // out-channel tile
  int n0 = (rem - (rem / gx) * gx) << 7;   // pixel tile (4 image rows)
  int lane = tid & 63;
  int wid = tid >> 6;                      // 0..3
  int wm = (wid & 1) << 6;
  int wn = (wid >> 1) << 6;
  int l31 = lane & 31;
  int kg = (lane >> 5) << 3;
  int yb = n0 >> 5;
  const u16* pXh = Xh + (i64)b * XPBq + (i64)(yb * 34) * Cq;  // 204-row window
  const u16* pXl = Xl + (i64)b * XPBq + (i64)(yb * 34) * Cq;
  int bbase[2];
#pragma unroll
  for (int nj = 0; nj < 2; nj++) {
    int nloc = wn + nj * 32 + l31;        // 0..127
    bbase[nj] = (nloc >> 5) * 34 + (nloc & 31);
  }
  f32x16 acc[2][2];
#pragma unroll
  for (int mi = 0; mi < 2; mi++)
#pragma unroll
    for (int nj = 0; nj < 2; nj++)
      acc[mi][nj] = (f32x16){0.f,0.f,0.f,0.f,0.f,0.f,0.f,0.f,0.f,0.f,0.f,0.f,0.f,0.f,0.f,0.f};

  for (int c0 = 0; c0 < Cq; c0 += 32) {
    // ---- stage B super-tile: 204 rows x 32 ch (hi + lo), once per c0 ----
    for (int e = tid; e < 816; e += 256) {   // 204 rows * 4 uint4
      int row = e >> 2, q = e & 3;
      i64 src = (i64)row * Cq + c0 + q * 8;
      *(uint4*)&Bs_h[row][q * 8] = *(const uint4*)(pXh + src);
      *(uint4*)&Bs_l[row][q * 8] = *(const uint4*)(pXl + src);
    }
    for (int tap = 0; tap < 9; tap++) {
      int doff = (tap / 3) * 34 + (tap % 3);
      // ---- stage A: weights for this (tap, c0), 128 rows x 32 ch ----
      {
        int r = tid >> 1, q0 = (tid & 1) << 1;
        i64 wo = (i64)tap * (Cq * Cq) + (i64)(m0 + r) * Cq + c0;
        *(uint4*)&As_h[r][q0 * 8]       = *(const uint4*)(Wh + wo + q0 * 8);
        *(uint4*)&As_h[r][(q0 + 1) * 8] = *(const uint4*)(Wh + wo + (q0 + 1) * 8);
        *(uint4*)&As_l[r][q0 * 8]       = *(const uint4*)(Wl + wo + q0 * 8);
        *(uint4*)&As_l[r][(q0 + 1) * 8] = *(const uint4*)(Wl + wo + (q0 + 1) * 8);
      }
      __syncthreads();
#pragma unroll
      for (int kstep = 0; kstep < 2; kstep++) {
        int kc = kstep * 16 + kg;
        bf16x8 ah[2], al[2], bh[2], bl[2];
#pragma unroll
        for (int mi = 0; mi < 2; mi++) {
          int row = wm + mi * 32 + l31;
          ah[mi] = *(const bf16x8*)&As_h[row][kc];
          al[mi] = *(const bf16x8*)&As_l[row][kc];
        }
#pragma unroll
        for (int nj = 0; nj < 2; nj++) {
          int row = bbase[nj] + doff;
          bh[nj] = *(const bf16x8*)&Bs_h[row][kc];
          bl[nj] = *(const bf16x8*)&Bs_l[row][kc];
        }
#pragma unroll
        for (int mi = 0; mi < 2; mi++)
#pragma unroll
          for (int nj = 0; nj < 2; nj++) {
            acc[mi][nj] = __builtin_amdgcn_mfma_f32_32x32x16_bf16(ah[mi], bh[nj], acc[mi][nj], 0, 0, 0);
            acc[mi][nj] = __builtin_amdgcn_mfma_f32_32x32x16_bf16(ah[mi], bl[nj], acc[mi][nj], 0, 0, 0);
            acc[mi][nj] = __builtin_amdgcn_mfma_f32_32x32x16_bf16(al[mi], bh[nj], acc[mi][nj], 0, 0, 0);
          }
      }
      __syncthreads();
    }
  }

#pragma unroll
  for (int mi = 0; mi < 2; mi++)
#pragma unroll
    for (int nj = 0; nj < 2; nj++) {
      int col_g = n0 + wn + nj * 32 + l31;
#pragma unroll
      for (int g = 0; g < 4; g++) {
        int row_b = m0 + wm + mi * 32 + g * 8 + ((lane >> 5) << 2);
#pragma unroll
        for (int r = 0; r < 4; r++) {
          float val = acc[mi][nj][g * 4 + r] + bias[row_b + r];
          out[(i64)b * (Cq * Nq) + (i64)(row_b + r) * Nq + col_g] = val;
        }
      }
    }
}

// ---------------- mean over N per (b,c): one wave per row ----------------
__global__ __launch_bounds__(256) void k_pool(const float* __restrict__ x, float* __restrict__ o) {
  int gw = (int)((blockIdx.x * 256 + threadIdx.x) >> 6);
  int ln = threadIdx.x & 63;
  const float* p = x + (i64)gw * Nq;
  float s = 0.f;
#pragma unroll
  for (int it = 0; it < 4; it++) {
    float4 v = *(const float4*)(p + ln * 4 + it * 256);
    s += v.x + v.y + v.z + v.w;
  }
#pragma unroll
  for (int off = 32; off > 0; off >>= 1) s += __shfl_xor(s, off, 64);
  if (ln == 0) o[gw] = s * (1.0f / 1024.0f);
}

// ---------------- gate MLP (32 blocks: 0-15 rgb, 16-31 dsm) ----------------
__global__ __launch_bounds__(128) void k_gate(
    const float* __restrict__ pooled, const float* __restrict__ w1,
    const float* __restrict__ b1, const float* __restrict__ w2,
    const float* __restrict__ b2, float* __restrict__ g) {
  __shared__ float pl[Cq];
  __shared__ float h[MIDq];
  int bb = blockIdx.x, tid = threadIdx.x;
  for (int c = tid; c < Cq; c += 128) pl[c] = pooled[bb * Cq + c];
  __syncthreads();
  float s = b1[tid];
  const float* wr = w1 + (i64)tid * Cq;
  for (int c = 0; c < Cq; c++) s = fmaf(wr[c], pl[c], s);
  h[tid] = fmaxf(s, 0.f);
  __syncthreads();
  if (tid < 2) {
    float t = b2[tid];
    const float* w2r = w2 + tid * MIDq;
    for (int m = 0; m < MIDq; m++) t = fmaf(w2r[m], h[m], t);
    g[bb * 2 + tid] = 1.0f / (1.0f + expf(-t));
  }
}

// ---------------- fused DCT -> gate -> iDCT per (b,c) 32x32 image ----------------
__global__ __launch_bounds__(256) void k_freq(
    const float* __restrict__ xr, const float* __restrict__ xd,
    float* __restrict__ yr, float* __restrict__ yd,
    const float* __restrict__ g_r, const float* __restrict__ g_d,
    const float* __restrict__ Dm, const float* __restrict__ lm) {
  __shared__ float Ds[32][36], Dt[32][36], Xs[32][36], T1[32][36];
  int bid = blockIdx.x;
  const float* x; float* y; const float* g;
  if (bid < Bq * Cq) {
    x = xr + (i64)bid * Nq; y = yr + (i64)bid * Nq; g = g_r + (bid >> 9) * 2;
  } else {
    int id = bid - Bq * Cq;
    x = xd + (i64)id * Nq; y = yd + (i64)id * Nq; g = g_d + (id >> 9) * 2;
  }
  int tid = threadIdx.x;
  int r_ = tid >> 3, j4 = (tid & 7) << 2;
  {
    float4 dv = *(const float4*)(Dm + tid * 4);
    *(float4*)&Ds[r_][j4] = dv;
    Dt[j4 + 0][r_] = dv.x; Dt[j4 + 1][r_] = dv.y;
    Dt[j4 + 2][r_] = dv.z; Dt[j4 + 3][r_] = dv.w;
    *(float4*)&Xs[r_][j4] = *(const float4*)(x + tid * 4);
  }
  float gl = g[0], gh = g[1];
  __syncthreads();
  float a0 = 0, a1 = 0, a2 = 0, a3 = 0;
#pragma unroll
  for (int h = 0; h < 32; h++) {
    float a = Ds[r_][h];
    float4 bv = *(const float4*)&Xs[h][j4];
    a0 = fmaf(a, bv.x, a0); a1 = fmaf(a, bv.y, a1);
    a2 = fmaf(a, bv.z, a2); a3 = fmaf(a, bv.w, a3);
  }
  *(float4*)&T1[r_][j4] = make_float4(a0, a1, a2, a3);
  __syncthreads();
  a0 = a1 = a2 = a3 = 0;
#pragma unroll
  for (int w = 0; w < 32; w++) {
    float a = T1[r_][w];
    float4 bv = *(const float4*)&Dt[w][j4];
    a0 = fmaf(a, bv.x, a0); a1 = fmaf(a, bv.y, a1);
    a2 = fmaf(a, bv.z, a2); a3 = fmaf(a, bv.w, a3);
  }
  {
    float4 mv = *(const float4*)(lm + r_ * 32 + j4);
    a0 *= fmaf(gl, mv.x, gh * (1.f - mv.x));
    a1 *= fmaf(gl, mv.y, gh * (1.f - mv.y));
    a2 *= fmaf(gl, mv.z, gh * (1.f - mv.z));
    a3 *= fmaf(gl, mv.w, gh * (1.f - mv.w));
  }
  __syncthreads();
  *(float4*)&Xs[r_][j4] = make_float4(a0, a1, a2, a3);
  __syncthreads();
  a0 = a1 = a2 = a3 = 0;
#pragma unroll
  for (int ii = 0; ii < 32; ii++) {
    float a = Dt[r_][ii];
    float4 bv = *(const float4*)&Xs[ii][j4];
    a0 = fmaf(a, bv.x, a0); a1 = fmaf(a, bv.y, a1);
    a2 = fmaf(a, bv.z, a2); a3 = fmaf(a, bv.w, a3);
  }
  __syncthreads();
  *(float4*)&T1[r_][j4] = make_float4(a0, a1, a2, a3);
  __syncthreads();
  a0 = a1 = a2 = a3 = 0;
#pragma unroll
  for (int jj = 0; jj < 32; jj++) {
    float a = T1[r_][jj];
    float4 bv = *(const float4*)&Ds[jj][j4];
    a0 = fmaf(a, bv.x, a0); a1 = fmaf(a, bv.y, a1);
    a2 = fmaf(a, bv.z, a2); a3 = fmaf(a, bv.w, a3);
  }
  *(float4*)(y + tid * 4) = make_float4(a0, a1, a2, a3);
}

// ---------------- row softmax + emit bf16 hi/lo ----------------
__global__ __launch_bounds__(256) void k_softmax_split(
    const float* __restrict__ sc, u16* __restrict__ ahi, u16* __restrict__ alo) {
  __shared__ float redm[4], reds[4];
  i64 row = blockIdx.x;
  const float* p = sc + row * (i64)Nq;
  int tid = threadIdx.x;
  float4 v = ((const float4*)p)[tid];
  float mx = fmaxf(fmaxf(v.x, v.y), fmaxf(v.z, v.w));
#pragma unroll
  for (int o = 32; o > 0; o >>= 1) mx = fmaxf(mx, __shfl_xor(mx, o, 64));
  if ((tid & 63) == 0) redm[tid >> 6] = mx;
  __syncthreads();
  mx = fmaxf(fmaxf(redm[0], redm[1]), fmaxf(redm[2], redm[3]));
  v.x = expf(v.x - mx); v.y = expf(v.y - mx);
  v.z = expf(v.z - mx); v.w = expf(v.w - mx);
  float s = v.x + v.y + v.z + v.w;
#pragma unroll
  for (int o = 32; o > 0; o >>= 1) s += __shfl_xor(s, o, 64);
  if ((tid & 63) == 0) reds[tid >> 6] = s;
  __syncthreads();
  s = reds[0] + reds[1] + reds[2] + reds[3];
  float inv = 1.0f / s;
  v.x *= inv; v.y *= inv; v.z *= inv; v.w *= inv;
  ushort4 h, l;
  h.x = f2bf(v.x); l.x = f2bf(v.x - bf2f(h.x));
  h.y = f2bf(v.y); l.y = f2bf(v.y - bf2f(h.y));
  h.z = f2bf(v.z); l.z = f2bf(v.z - bf2f(h.z));
  h.w = f2bf(v.w); l.w = f2bf(v.w - bf2f(h.w));
  *(ushort4*)(ahi + row * Nq + tid * 4) = h;
  *(ushort4*)(alo + row * Nq + tid * 4) = l;
}

// ---------------- channel attention MLP ----------------
__global__ __launch_bounds__(512) void k_ca(
    const float* __restrict__ pooled, const float* __restrict__ w1,
    const float* __restrict__ b1, const float* __restrict__ w2,
    const float* __restrict__ b2, float* __restrict__ wt) {
  __shared__ float pl[Cq];
  __shared__ float h[MIDq];
  int b = blockIdx.x, tid = threadIdx.x;
  pl[tid] = pooled[b * Cq + tid];
  __syncthreads();
  if (tid < MIDq) {
    float s = b1[tid];
    const float* wr = w1 + (i64)tid * Cq;
    for (int c = 0; c < Cq; c++) s = fmaf(wr[c], pl[c], s);
    h[tid] = fmaxf(s, 0.f);
  }
  __syncthreads();
  float s = b2[tid];
  const float* wr = w2 + (i64)tid * MIDq;
  for (int m = 0; m < MIDq; m++) s = fmaf(wr[m], h[m], s);
  wt[b * Cq + tid] = 1.0f / (1.0f + expf(-s));
}

// ---------------- final: out = rgb_p + spatial * weight[b,c] ----------------
__global__ __launch_bounds__(256) void k_final(
    const float* __restrict__ rgbp, const float* __restrict__ sp,
    const float* __restrict__ wt, float* __restrict__ out) {
  i64 idx = (i64)blockIdx.x * 256 + threadIdx.x;
  float4 a = ((const float4*)rgbp)[idx];
  float4 s = ((const float4*)sp)[idx];
  float w = wt[idx >> 8];
  float4 r;
  r.x = fmaf(s.x, w, a.x); r.y = fmaf(s.y, w, a.y);
  r.z = fmaf(s.z, w, a.z); r.w = fmaf(s.w, w, a.w);
  ((float4*)out)[idx] = r;
}

extern "C" void kernel_launch(void* const* d_in, const int* in_sizes, int n_in,
                              void* d_out, int out_size, void* d_ws, size_t ws_size,
                              hipStream_t stream) {
  (void)in_sizes; (void)n_in; (void)out_size; (void)ws_size;
  const float* rgb    = (const float*)d_in[0];
  const float* dsm    = (const float*)d_in[1];
  const float* rgb_w  = (const float*)d_in[2];
  const float* rgb_b  = (const float*)d_in[3];
  const float* dsm_w  = (const float*)d_in[4];
  const float* dsm_b  = (const float*)d_in[5];
  const float* gate_w1 = (const float*)d_in[6];
  const float* gate_b1 = (const float*)d_in[7];
  const float* gate_w2 = (const float*)d_in[8];
  const float* gate_b2 = (const float*)d_in[9];
  const float* q_w = (const float*)d_in[10];
  const float* q_b = (const float*)d_in[11];
  const float* k_w = (const float*)d_in[12];
  const float* k_b = (const float*)d_in[13];
  const float* v_w = (const float*)d_in[14];
  const float* v_b = (const float*)d_in[15];
  const float* sp_w = (const float*)d_in[16];
  const float* sp_b = (const float*)d_in[17];
  const float* ca_w1 = (const float*)d_in[18];
  const float* ca_b1 = (const float*)d_in[19];
  const float* ca_w2 = (const float*)d_in[20];
  const float* ca_b2 = (const float*)d_in[21];

  const i64 S  = (i64)Bq * Cq * Nq;      // 8,388,608
  const i64 SU = S;
  const i64 WE = (i64)Cq * Cq;           // 262144
  const i64 XPT = (i64)Bq * XPBq;        // 9,469,952

  float* wsf = (float*)d_ws;
  // fp32 slots (4 x S)
  float* rgbp   = wsf;                   // slot0, live to end
  float* dsmp   = wsf + S;               // slot1 -> scores(lo half) -> xpad
  float* rgbf   = wsf + 2 * S;           // slot2 -> scores(hi half) -> xpad tail
  float* dsmf   = wsf + 3 * S;           // slot3 -> spatial
  float* scores  = dsmp;                 // spans slots 1-2
  float* spatial = dsmf;
  // xpad (conv3 input) overlays the dead scores region after softmax
  u16* XPh = (u16*)dsmp;
  u16* XPl = XPh + XPT;                  // total 75.8 MB < 2S floats
  // small fp32 region (32768 floats)
  float* smallr = wsf + 4 * S;
  float* Dm     = smallr;                // 1024
  float* lm     = smallr + 1024;         // 1024
  float* pooled = smallr + 2048;         // 16384 (2 * B*C)
  float* g_all  = smallr + 18432;        // 64
  float* wt     = smallr + 18496;        // 8192
  // bf16 units
  u16* ub = (u16*)(wsf + 4 * S + 32768);
  u16* U0 = ub;          u16* U1 = ub + SU;
  u16* U2 = ub + 2 * SU;
  u16* U4 = ub + 4 * SU; u16* U5 = ub + 5 * SU;
  // split weights
  u16* wb = ub + 6 * SU;
  u16* rgbw_h = wb;           u16* rgbw_l = wb + WE;
  u16* dsmw_h = wb + 2 * WE;  u16* dsmw_l = wb + 3 * WE;
  u16* qw_h   = wb + 4 * WE;  u16* qw_l   = wb + 5 * WE;
  u16* kw_h   = wb + 6 * WE;  u16* kw_l   = wb + 7 * WE;
  u16* vw_h   = wb + 8 * WE;  u16* vw_l   = wb + 9 * WE;
  u16* w9h    = wb + 10 * WE; u16* w9l    = wb + 19 * WE;

  const i64 sT = (i64)Nq * Cq;       // 524288
  const i64 sS = (i64)Nq * Nq;       // 1048576
  const float rsqc = 0.044194173824159216f;
  const int NOSPLIT = 1 << 20;

  k_prep<<<1537, 256, 0, stream>>>(rgb_w, dsm_w, q_w, k_w, v_w, sp_w,
                                   rgbw_h, rgbw_l, dsmw_h, dsmw_l, qw_h, qw_l,
                                   kw_h, kw_l, vw_h, vw_l, w9h, w9l, Dm, lm);

  dim3 gW(Nq / 128, Cq / 128, Bq);    // M=512,N=1024 -> (8,4,16)
  dim3 gS(Nq / 128, Nq / 128, Bq);    // M=N=1024 -> (8,8,16)
  dim3 gProj(Nq / 128, 2 * (Cq / 128), Bq);   // merged rgb_p + dsm_p: (8,8,16)
  dim3 gQK(Cq / 128, 2 * (Nq / 128), Bq);     // merged q_t + k_t: (4,16,16)

  // merged: rgb_p (set1) + dsm_p (set2), ySplit=4
  k_gemm<<<gProj, 512, 0, stream>>>(rgbw_h, rgbw_l, nullptr, 0, 0,
                                    nullptr, nullptr, rgb, 1, sT,
                                    rgb_b, 1, 1.0f, Cq, Nq, Cq,
                                    rgbp, nullptr, nullptr, sT, 0,
                                    Cq / 128,
                                    dsmw_h, dsmw_l, nullptr,
                                    nullptr, nullptr, dsm,
                                    dsm_b, dsmp, nullptr, nullptr);

  k_pool<<<(2 * Bq * Cq) / 4, 256, 0, stream>>>(rgbp, pooled);
  k_gate<<<32, 128, 0, stream>>>(pooled, gate_w1, gate_b1, gate_w2, gate_b2, g_all);

  k_freq<<<2 * Bq * Cq, 256, 0, stream>>>(rgbp, dsmp, rgbf, dsmf, g_all, g_all + 32, Dm, lm);

  // merged: q_t (set1, A=rgbf) + k_t (set2, A=dsmf), ySplit=8
  k_gemm<<<gQK, 512, 0, stream>>>(nullptr, nullptr, rgbf, 1, sT,
                                  qw_h, qw_l, nullptr, 0, 0,
                                  q_b, 2, 1.0f, Nq, Cq, Cq,
                                  nullptr, U4, U5, sT, 1,
                                  Nq / 128,
                                  nullptr, nullptr, dsmf,
                                  kw_h, kw_l, nullptr,
                                  k_b, nullptr, U0, U1);

  // scores[n][m] fp32 = q_t x k_t^T * 1/sqrt(C)
  k_gemm<<<gS, 512, 0, stream>>>(U4, U5, nullptr, 0, sT,
                                 U0, U1, nullptr, 0, sT,
                                 nullptr, 0, rsqc, Nq, Nq, Cq,
                                 scores, nullptr, nullptr, sS, 0,
                                 NOSPLIT,
                                 nullptr, nullptr, nullptr,
                                 nullptr, nullptr, nullptr,
                                 nullptr, nullptr, nullptr, nullptr);
  // v[c][m] split = v_w x dsmf -> U4,U5
  k_gemm<<<gW, 512, 0, stream>>>(vw_h, vw_l, nullptr, 0, 0,
                                 nullptr, nullptr, dsmf, 1, sT,
                                 v_b, 1, 1.0f, Cq, Nq, Cq,
                                 nullptr, U4, U5, sT, 1,
                                 NOSPLIT,
                                 nullptr, nullptr, nullptr,
                                 nullptr, nullptr, nullptr,
                                 nullptr, nullptr, nullptr, nullptr);
  // softmax -> attn hi U0, lo U2 (scores region becomes dead after this)
  k_softmax_split<<<Bq * Nq, 256, 0, stream>>>(scores, U0, U2);
  // zero xpad borders (in the now-dead scores region)
  k_zero_border<<<dim3(132, Bq, 2), 64, 0, stream>>>(XPh);
  // PV: xpad[pr][c] (split) = v x attn^T, written pad-transposed directly
  k_gemm<<<gW, 512, 0, stream>>>(U4, U5, nullptr, 0, sT,
                                 U0, U2, nullptr, 0, sS,
                                 nullptr, 0, 1.0f, Cq, Nq, Nq,
                                 nullptr, XPh, XPl, XPBq, 2,
                                 NOSPLIT,
                                 nullptr, nullptr, nullptr,
                                 nullptr, nullptr, nullptr,
                                 nullptr, nullptr, nullptr, nullptr);

  // conv3 via MFMA (32x32x16, 256 threads, B-super-tile)
  k_conv3_mfma<<<dim3(Nq / 128, Cq / 128, Bq), 256, 0, stream>>>(
      w9h, w9l, XPh, XPl, sp_b, spatial);

  k_pool<<<(Bq * Cq) / 4, 256, 0, stream>>>(spatial, pooled);
  k_ca<<<Bq, 512, 0, stream>>>(pooled, ca_w1, ca_b1, ca_w2, ca_b2, wt);

  k_final<<<(int)(S / 4 / 256), 256, 0, stream>>>(rgbp, spatial, wt, (float*)d_out);
}